// Round 1
// baseline (3808.544 us; speedup 1.0000x reference)
//
#include <hip/hip_runtime.h>

#define NN 10000
#define NE 100000
#define ND 128
#define NB 20
#define NIR 224
#define NH 352
#define SD 480

// CG / normalization constants (hand-derived from the reference _cg_tables)
#define CR   0.70710678118654752f  // 1/sqrt2
#define CA   0.40824829046386302f  // 1/sqrt6
#define HA   0.20412414523193151f  // CA/2
#define HR   0.35355339059327376f  // CR/2
#define C110 0.57735026918962576f  // 1/sqrt3   (110/011/101)
#define C220 0.44721359549995794f  // 1/sqrt5   (220/022/202)
#define C111 0.40824829046386302f  // 1/sqrt6
#define C11X 0.44721359549995794f  // 1/sqrt5   (112/121/211: ||S||_F = sqrt5)
#define C221 0.36514837167011074f  // 1/sqrt7.5 (221/122/212)
#define C222 0.58554004376912270f  // 1/sqrt(35/12)
#define S32  0.86602540378443865f  // sqrt3/2
#define PW0  0.066815310478106094f // sqrt(1/224)
#define PW1  0.088388347648318447f // sqrt(3/384)
#define PW2  0.11918321088232916f  // sqrt(5/352)

__device__ __forceinline__ float warpReduceSum(float v) {
  #pragma unroll
  for (int off = 32; off > 0; off >>= 1) v += __shfl_down(v, off, 64);
  return v;
}

// ---------------- Kernel 1: scalar LN + O3 LN (one block of 128 per node) ----
__global__ __launch_bounds__(128) void node_ln_kernel(
    const float* __restrict__ xs, const float* __restrict__ xsph,
    const float* __restrict__ lnw, const float* __restrict__ lnb,
    const float* __restrict__ o3w, const float* __restrict__ o3b,
    float* __restrict__ s_in, float* __restrict__ sph_in,
    float* __restrict__ out0, float* __restrict__ out1)
{
  const int n = blockIdx.x, t = threadIdx.x;
  __shared__ float red[4];

  auto reduce2 = [&](float a, float b) {
    a = warpReduceSum(a); b = warpReduceSum(b);
    if ((t & 63) == 0) { red[(t >> 6) * 2] = a; red[(t >> 6) * 2 + 1] = b; }
    __syncthreads();
    float ra = red[0] + red[2], rb = red[1] + red[3];
    __syncthreads();
    return make_float2(ra, rb);
  };

  // scalar LayerNorm over 128
  float x = xs[n * ND + t];
  float2 sr = reduce2(x, x * x);
  float mu = sr.x * (1.f / ND);
  float var = sr.y * (1.f / ND) - mu * mu;
  float y = (x - mu) * rsqrtf(var + 1e-5f) * lnw[t] + lnb[t];
  s_in[n * ND + t] = y; out0[n * ND + t] = y;

  // O3 LN l=0 (center over mul, norm = mean of centered^2, +bias)
  float f = xsph[n * SD + t];
  float2 r0 = reduce2(f, f * f);
  float m0 = r0.x * (1.f / 128.f);
  float nrm0 = r0.y * (1.f / 128.f) - m0 * m0;
  float y0 = (f - m0) * rsqrtf(nrm0 + 1e-5f) * o3w[t] + o3b[t];
  sph_in[n * SD + t] = y0; out1[n * SD + t] = y0;

  // l=1: 192 elements, norm over all, weight per mul (idx/3)
  float f1a = xsph[n * SD + 128 + t];
  float f1b = (t < 64) ? xsph[n * SD + 256 + t] : 0.f;
  float2 r1 = reduce2(f1a * f1a + f1b * f1b, 0.f);
  float rs1 = rsqrtf(r1.x * (1.f / 192.f) + 1e-5f);
  float ya = f1a * rs1 * o3w[128 + t / 3];
  sph_in[n * SD + 128 + t] = ya; out1[n * SD + 128 + t] = ya;
  if (t < 64) {
    float yb = f1b * rs1 * o3w[128 + (128 + t) / 3];
    sph_in[n * SD + 256 + t] = yb; out1[n * SD + 256 + t] = yb;
  }

  // l=2: 160 elements, weight per mul (idx/5)
  float f2a = xsph[n * SD + 320 + t];
  float f2b = (t < 32) ? xsph[n * SD + 448 + t] : 0.f;
  float2 r2 = reduce2(f2a * f2a + f2b * f2b, 0.f);
  float rs2 = rsqrtf(r2.x * (1.f / 160.f) + 1e-5f);
  float y2a = f2a * rs2 * o3w[192 + t / 5];
  sph_in[n * SD + 320 + t] = y2a; out1[n * SD + 320 + t] = y2a;
  if (t < 32) {
    float y2b = f2b * rs2 * o3w[192 + (128 + t) / 5];
    sph_in[n * SD + 448 + t] = y2b; out1[n * SD + 448 + t] = y2b;
  }
}

// ---------------- Kernel 2: node MLP (silu(x@W1+b1)@W2+b2), 8 nodes/block ----
#define NPB 8
__global__ __launch_bounds__(256) void mlp_kernel(
    const float* __restrict__ s_in, const float* __restrict__ w1,
    const float* __restrict__ b1, const float* __restrict__ w2,
    const float* __restrict__ b2, float* __restrict__ s_out)
{
  __shared__ float sIn[NPB][ND];
  __shared__ float sH[NPB][ND];
  const int t = threadIdx.x;
  const int n0 = blockIdx.x * NPB;
  for (int i = t; i < NPB * ND; i += 256) sIn[i >> 7][i & 127] = s_in[n0 * ND + i];
  __syncthreads();
  {
    const int j = t & 127, g = t >> 7;
    float acc[4] = {0.f, 0.f, 0.f, 0.f};
    for (int k = 0; k < ND; ++k) {
      float w = w1[k * ND + j];
      #pragma unroll
      for (int i = 0; i < 4; ++i) acc[i] = fmaf(sIn[g + 2 * i][k], w, acc[i]);
    }
    #pragma unroll
    for (int i = 0; i < 4; ++i) {
      float z = acc[i] + b1[j];
      sH[g + 2 * i][j] = z / (1.f + __expf(-z));
    }
  }
  __syncthreads();
  for (int jb = 0; jb < 2; ++jb) {
    int j = jb * 256 + t;
    if (j < NH) {
      float acc[NPB];
      #pragma unroll
      for (int i = 0; i < NPB; ++i) acc[i] = b2[j];
      for (int k = 0; k < ND; ++k) {
        float w = w2[k * NH + j];
        #pragma unroll
        for (int i = 0; i < NPB; ++i) acc[i] = fmaf(sH[i][k], w, acc[i]);
      }
      #pragma unroll
      for (int i = 0; i < NPB; ++i) s_out[(n0 + i) * NH + j] = acc[i];
    }
  }
}

// ---------------- Kernel 3: scalar messages (fo[:,224:352] scatter) ---------
__global__ __launch_bounds__(256) void scalar_msg_kernel(
    const float* __restrict__ rbf, const float* __restrict__ rbf_w,
    const float* __restrict__ s_out, const int* __restrict__ ei,
    float* __restrict__ out0)
{
  __shared__ float srbf[2][NB];
  const int t = threadIdx.x & 127, el = threadIdx.x >> 7;
  const int e = blockIdx.x * 2 + el;
  if (t < NB) srbf[el][t] = rbf[e * NB + t];
  __syncthreads();
  const int dst = ei[e], src = ei[NE + e];
  float filt = 0.f;
  #pragma unroll
  for (int b = 0; b < NB; ++b) filt = fmaf(srbf[el][b], rbf_w[b * NH + NIR + t], filt);
  float msg = s_out[src * NH + NIR + t] * filt;
  unsafeAtomicAdd(&out0[dst * ND + t], msg);
}

// ---------------- Kernel 4: TP l3=0 (U=224 -> N=128) ------------------------
// tile ET=16 edges; W cat in LDS; gate staged; T computed on the fly.
__global__ __launch_bounds__(256) void tp0_kernel(
    const float* __restrict__ rbf, const float* __restrict__ rbf_w,
    const float* __restrict__ rsh, const int* __restrict__ ei,
    const float* __restrict__ s_out, const float* __restrict__ sph_in,
    const float* __restrict__ tpw, float* __restrict__ out1)
{
  __shared__ float Wl[224 * 128];
  __shared__ float Tl[16 * 228];
  __shared__ float Gl[16 * 224];
  __shared__ float Rsh[16][12];
  __shared__ int Esrc[16]; __shared__ int Edst[16];
  __shared__ float Erbf[16][NB];
  const int t = threadIdx.x;

  for (int idx = t; idx < 224 * 128; idx += 256) {
    int u = idx >> 7, j = idx & 127; int off;
    if (u < 128) off = 0 + u * 128;
    else if (u < 192) off = 16384 + (u - 128) * 128;
    else off = 24576 + (u - 192) * 128;
    Wl[idx] = tpw[off + j];
  }
  __syncthreads();

  for (int tile = blockIdx.x; tile < NE / 16; tile += gridDim.x) {
    __syncthreads();
    const int e0 = tile * 16;
    for (int i = t; i < 16; i += 256) { Edst[i] = ei[e0 + i]; Esrc[i] = ei[NE + e0 + i]; }
    for (int i = t; i < 16 * 9; i += 256) Rsh[i / 9][i % 9] = rsh[(e0 + i / 9) * 9 + i % 9];
    for (int i = t; i < 16 * NB; i += 256) Erbf[i / NB][i % NB] = rbf[(e0 + i / NB) * NB + i % NB];
    __syncthreads();
    // gate
    for (int idx = t; idx < 16 * 224; idx += 256) {
      int e = idx / 224, gi = idx - e * 224;
      float fl = 0.f;
      #pragma unroll
      for (int b = 0; b < NB; ++b) fl = fmaf(Erbf[e][b], rbf_w[b * NH + gi], fl);
      Gl[idx] = s_out[Esrc[e] * NH + gi] * fl;
    }
    __syncthreads();
    // T0
    for (int idx = t; idx < 16 * 224; idx += 256) {
      int e = idx / 224, u = idx - e * 224;
      const float* sph = sph_in + (long)Esrc[e] * SD;
      const float* R = Rsh[e];
      float tv;
      if (u < 128) {
        tv = R[0] * sph[u] * Gl[e * 224 + u];
      } else if (u < 192) {
        int up = u - 128; float gg = Gl[e * 224 + 128 + up];
        const float* b = sph + 128 + up * 3;
        tv = C110 * gg * (b[0] * R[1] + b[1] * R[2] + b[2] * R[3]);
      } else {
        int up = u - 192; float gg = Gl[e * 224 + 192 + up];
        const float* g = sph + 320 + up * 5;
        tv = C220 * gg * (g[0] * R[4] + g[1] * R[5] + g[2] * R[6] + g[3] * R[7] + g[4] * R[8]);
      }
      Tl[e * 228 + u] = tv;
    }
    __syncthreads();
    // GEMM: 2 row-groups x 128 cols, 8 rows/thread
    {
      const int j = t & 127, rg = t >> 7;
      float acc[8] = {0.f,0.f,0.f,0.f,0.f,0.f,0.f,0.f};
      for (int u0 = 0; u0 < 224; u0 += 4) {
        const float wa = Wl[(u0 + 0) * 128 + j];
        const float wb = Wl[(u0 + 1) * 128 + j];
        const float wc = Wl[(u0 + 2) * 128 + j];
        const float wd = Wl[(u0 + 3) * 128 + j];
        #pragma unroll
        for (int i = 0; i < 8; ++i) {
          const float4 tv = *(const float4*)&Tl[(rg * 8 + i) * 228 + u0];
          acc[i] = fmaf(tv.x, wa, acc[i]);
          acc[i] = fmaf(tv.y, wb, acc[i]);
          acc[i] = fmaf(tv.z, wc, acc[i]);
          acc[i] = fmaf(tv.w, wd, acc[i]);
        }
      }
      #pragma unroll
      for (int i = 0; i < 8; ++i)
        unsafeAtomicAdd(&out1[(long)Edst[rg * 8 + i] * SD + j], PW0 * acc[i]);
    }
    __syncthreads();
  }
}

// ---------------- Kernel 5: TP l3=1 (U=384 -> N=64, 3 k-slices) --------------
__global__ __launch_bounds__(256) void tp1_kernel(
    const float* __restrict__ rbf, const float* __restrict__ rbf_w,
    const float* __restrict__ rsh, const int* __restrict__ ei,
    const float* __restrict__ s_out, const float* __restrict__ sph_in,
    const float* __restrict__ tpw, float* __restrict__ out1)
{
  __shared__ float Wl[384 * 64];
  __shared__ float X1[16 * 481];
  __shared__ float Tl[16 * 388];
  __shared__ float Rsh[16][12];
  __shared__ int Esrc[16]; __shared__ int Edst[16];
  __shared__ float Erbf[16][NB];
  const int t = threadIdx.x;

  for (int idx = t; idx < 384 * 64; idx += 256) {
    int u = idx >> 6, j = idx & 63; int off;
    if (u < 128) off = 28672 + u * 64;
    else if (u < 192) off = 36864 + (u - 128) * 64;
    else if (u < 256) off = 40960 + (u - 192) * 64;
    else if (u < 320) off = 45056 + (u - 256) * 64;
    else if (u < 352) off = 49152 + (u - 320) * 64;
    else off = 51200 + (u - 352) * 64;
    Wl[idx] = tpw[off + j];
  }
  __syncthreads();

  for (int tile = blockIdx.x; tile < NE / 16; tile += gridDim.x) {
    __syncthreads();
    const int e0 = tile * 16;
    for (int i = t; i < 16; i += 256) { Edst[i] = ei[e0 + i]; Esrc[i] = ei[NE + e0 + i]; }
    for (int i = t; i < 16 * 9; i += 256) Rsh[i / 9][i % 9] = rsh[(e0 + i / 9) * 9 + i % 9];
    for (int i = t; i < 16 * NB; i += 256) Erbf[i / NB][i % NB] = rbf[(e0 + i / NB) * NB + i % NB];
    __syncthreads();
    // x1 = gated spherical
    for (int idx = t; idx < 16 * SD; idx += 256) {
      int e = idx / SD, c = idx - e * SD;
      int gi;
      if (c < 128) gi = c;
      else if (c < 320) gi = 128 + (c - 128) / 3;
      else gi = 192 + (c - 320) / 5;
      float fl = 0.f;
      #pragma unroll
      for (int b = 0; b < NB; ++b) fl = fmaf(Erbf[e][b], rbf_w[b * NH + gi], fl);
      X1[e * 481 + c] = sph_in[(long)Esrc[e] * SD + c] * (s_out[Esrc[e] * NH + gi] * fl);
    }
    __syncthreads();

    for (int k = 0; k < 3; ++k) {
      // T1 slice k
      for (int idx = t; idx < 16 * 384; idx += 256) {
        int e = idx / 384, u = idx - e * 384;
        const float* R = Rsh[e];
        const float* x1 = &X1[e * 481];
        const float s = R[0], v0 = R[1], v1 = R[2], v2 = R[3];
        float tv;
        if (u < 128) {
          tv = C110 * x1[u] * R[1 + k];
        } else if (u < 192) {
          tv = C110 * s * x1[128 + (u - 128) * 3 + k];
        } else if (u < 256) {
          const float* b = &x1[128 + (u - 192) * 3];
          int ka = (k + 1 < 3) ? k + 1 : k - 2;
          int kb = (k + 2 < 3) ? k + 2 : k - 1;
          tv = C111 * (b[ka] * R[1 + kb] - b[kb] * R[1 + ka]);
        } else if (u < 320) {
          const float* b = &x1[128 + (u - 256) * 3];
          const float w0 = R[4], w1 = R[5], w2 = R[6], w3 = R[7], w4 = R[8];
          if (k == 0)      tv = C11X * ((-CA * w2 + CR * w4) * b[0] + CR * w0 * b[1] + CR * w3 * b[2]);
          else if (k == 1) tv = C11X * (CR * w0 * b[0] + (-CA * w2 - CR * w4) * b[1] + CR * w1 * b[2]);
          else             tv = C11X * (CR * w3 * b[0] + CR * w1 * b[1] + 2.f * CA * w2 * b[2]);
        } else if (u < 352) {
          const float* g = &x1[320 + (u - 320) * 5];
          if (k == 0)      tv = C11X * ((-CA * g[2] + CR * g[4]) * v0 + CR * g[0] * v1 + CR * g[3] * v2);
          else if (k == 1) tv = C11X * (CR * g[0] * v0 + (-CA * g[2] - CR * g[4]) * v1 + CR * g[1] * v2);
          else             tv = C11X * (CR * g[3] * v0 + CR * g[1] * v1 + 2.f * CA * g[2] * v2);
        } else {
          const float* g = &x1[320 + (u - 352) * 5];
          const float w0 = R[4], w1 = R[5], w2 = R[6], w3 = R[7], w4 = R[8];
          if (k == 0)      tv = C221 * (0.5f * (g[0] * w3 - g[3] * w0) + S32 * (g[1] * w2 - g[2] * w1) + 0.5f * (g[1] * w4 - g[4] * w1));
          else if (k == 1) tv = C221 * (-0.5f * (g[0] * w1 - g[1] * w0) + S32 * (g[2] * w3 - g[3] * w2) + 0.5f * (g[3] * w4 - g[4] * w3));
          else             tv = C221 * (-(g[0] * w4 - g[4] * w0) - 0.5f * (g[1] * w3 - g[3] * w1));
        }
        Tl[e * 388 + u] = tv;
      }
      __syncthreads();
      // GEMM: 4 row-groups x 64 cols, 4 rows/thread
      {
        const int j = t & 63, rg = t >> 6;
        float acc[4] = {0.f,0.f,0.f,0.f};
        for (int u0 = 0; u0 < 384; u0 += 4) {
          const float wa = Wl[(u0 + 0) * 64 + j];
          const float wb = Wl[(u0 + 1) * 64 + j];
          const float wc = Wl[(u0 + 2) * 64 + j];
          const float wd = Wl[(u0 + 3) * 64 + j];
          #pragma unroll
          for (int i = 0; i < 4; ++i) {
            const float4 tv = *(const float4*)&Tl[(rg * 4 + i) * 388 + u0];
            acc[i] = fmaf(tv.x, wa, acc[i]);
            acc[i] = fmaf(tv.y, wb, acc[i]);
            acc[i] = fmaf(tv.z, wc, acc[i]);
            acc[i] = fmaf(tv.w, wd, acc[i]);
          }
        }
        #pragma unroll
        for (int i = 0; i < 4; ++i)
          unsafeAtomicAdd(&out1[(long)Edst[rg * 4 + i] * SD + 128 + j * 3 + k], PW1 * acc[i]);
      }
      __syncthreads();
    }
  }
}

// ---------------- Kernel 6: TP l3=2 (U=352 -> N=32, 5 k-slices) --------------
__global__ __launch_bounds__(256) void tp2_kernel(
    const float* __restrict__ rbf, const float* __restrict__ rbf_w,
    const float* __restrict__ rsh, const int* __restrict__ ei,
    const float* __restrict__ s_out, const float* __restrict__ sph_in,
    const float* __restrict__ tpw, float* __restrict__ out1)
{
  __shared__ float Wl[352 * 32];
  __shared__ float X1[32 * 481];
  __shared__ float Tl[32 * 356];
  __shared__ float Rsh[32][12];
  __shared__ int Esrc[32]; __shared__ int Edst[32];
  __shared__ float Erbf[32][NB];
  const int t = threadIdx.x;

  for (int idx = t; idx < 352 * 32; idx += 256) {
    int u = idx >> 5, j = idx & 31; int off;
    if (u < 128) off = 53248 + u * 32;
    else if (u < 192) off = 57344 + (u - 128) * 32;
    else if (u < 256) off = 59392 + (u - 192) * 32;
    else if (u < 288) off = 61440 + (u - 256) * 32;
    else if (u < 320) off = 62464 + (u - 288) * 32;
    else off = 63488 + (u - 320) * 32;
    Wl[idx] = tpw[off + j];
  }
  __syncthreads();

  for (int tile = blockIdx.x; tile < NE / 32; tile += gridDim.x) {
    __syncthreads();
    const int e0 = tile * 32;
    for (int i = t; i < 32; i += 256) { Edst[i] = ei[e0 + i]; Esrc[i] = ei[NE + e0 + i]; }
    for (int i = t; i < 32 * 9; i += 256) Rsh[i / 9][i % 9] = rsh[(e0 + i / 9) * 9 + i % 9];
    for (int i = t; i < 32 * NB; i += 256) Erbf[i / NB][i % NB] = rbf[(e0 + i / NB) * NB + i % NB];
    __syncthreads();
    for (int idx = t; idx < 32 * SD; idx += 256) {
      int e = idx / SD, c = idx - e * SD;
      int gi;
      if (c < 128) gi = c;
      else if (c < 320) gi = 128 + (c - 128) / 3;
      else gi = 192 + (c - 320) / 5;
      float fl = 0.f;
      #pragma unroll
      for (int b = 0; b < NB; ++b) fl = fmaf(Erbf[e][b], rbf_w[b * NH + gi], fl);
      X1[e * 481 + c] = sph_in[(long)Esrc[e] * SD + c] * (s_out[Esrc[e] * NH + gi] * fl);
    }
    __syncthreads();

    for (int K = 0; K < 5; ++K) {
      for (int idx = t; idx < 32 * 352; idx += 256) {
        int e = idx / 352, u = idx - e * 352;
        const float* R = Rsh[e];
        const float* x1 = &X1[e * 481];
        const float s = R[0], v0 = R[1], v1 = R[2], v2 = R[3];
        const float w0 = R[4], w1 = R[5], w2 = R[6], w3 = R[7], w4 = R[8];
        float tv;
        if (u < 128) {
          tv = C220 * x1[u] * R[4 + K];
        } else if (u < 192) {
          const float* b = &x1[128 + (u - 128) * 3];
          if (K == 0)      tv = C11X * CR * (b[0] * v1 + b[1] * v0);
          else if (K == 1) tv = C11X * CR * (b[1] * v2 + b[2] * v1);
          else if (K == 2) tv = C11X * CA * (-b[0] * v0 - b[1] * v1 + 2.f * b[2] * v2);
          else if (K == 3) tv = C11X * CR * (b[0] * v2 + b[2] * v0);
          else             tv = C11X * CR * (b[0] * v0 - b[1] * v1);
        } else if (u < 256) {
          const float* b = &x1[128 + (u - 192) * 3];
          if (K == 0)      tv = C221 * (0.5f * w1 * b[1] - 0.5f * w3 * b[0] + w4 * b[2]);
          else if (K == 1) tv = C221 * (-0.5f * w0 * b[1] - S32 * w2 * b[0] + 0.5f * w3 * b[2] - 0.5f * w4 * b[0]);
          else if (K == 2) tv = C221 * (S32 * (w1 * b[0] - w3 * b[1]));
          else if (K == 3) tv = C221 * (0.5f * w0 * b[0] - 0.5f * w1 * b[2] + S32 * w2 * b[1] - 0.5f * w4 * b[1]);
          else             tv = C221 * (-w0 * b[2] + 0.5f * w1 * b[0] + 0.5f * w3 * b[1]);
        } else if (u < 288) {
          tv = C220 * s * x1[320 + (u - 256) * 5 + K];
        } else if (u < 320) {
          const float* g = &x1[320 + (u - 288) * 5];
          if (K == 0)      tv = C221 * (0.5f * g[1] * v1 - 0.5f * g[3] * v0 + g[4] * v2);
          else if (K == 1) tv = C221 * (-0.5f * g[0] * v1 - S32 * g[2] * v0 + 0.5f * g[3] * v2 - 0.5f * g[4] * v0);
          else if (K == 2) tv = C221 * (S32 * (g[1] * v0 - g[3] * v1));
          else if (K == 3) tv = C221 * (0.5f * g[0] * v0 - 0.5f * g[1] * v2 + S32 * g[2] * v1 - 0.5f * g[4] * v1);
          else             tv = C221 * (-g[0] * v2 + 0.5f * g[1] * v0 + 0.5f * g[3] * v1);
        } else {
          const float* g = &x1[320 + (u - 320) * 5];
          if (K == 0)      tv = C222 * (-CA * (g[0] * w2 + g[2] * w0) + HR * (g[1] * w3 + g[3] * w1));
          else if (K == 1) tv = C222 * (HA * (g[1] * w2 + g[2] * w1) + HR * (g[0] * w3 + g[3] * w0) - HR * (g[1] * w4 + g[4] * w1));
          else if (K == 2) tv = C222 * (-CA * g[0] * w0 + HA * g[1] * w1 + CA * g[2] * w2 + HA * g[3] * w3 - CA * g[4] * w4);
          else if (K == 3) tv = C222 * (HR * (g[0] * w1 + g[1] * w0) + HA * (g[2] * w3 + g[3] * w2) + HR * (g[3] * w4 + g[4] * w3));
          else             tv = C222 * (-HR * g[1] * w1 + HR * g[3] * w3 - CA * (g[2] * w4 + g[4] * w2));
        }
        Tl[e * 356 + u] = tv;
      }
      __syncthreads();
      // GEMM: 8 row-groups x 32 cols, 4 rows/thread
      {
        const int j = t & 31, rg = t >> 5;
        float acc[4] = {0.f,0.f,0.f,0.f};
        for (int u0 = 0; u0 < 352; u0 += 4) {
          const float wa = Wl[(u0 + 0) * 32 + j];
          const float wb = Wl[(u0 + 1) * 32 + j];
          const float wc = Wl[(u0 + 2) * 32 + j];
          const float wd = Wl[(u0 + 3) * 32 + j];
          #pragma unroll
          for (int i = 0; i < 4; ++i) {
            const float4 tv = *(const float4*)&Tl[(rg * 4 + i) * 356 + u0];
            acc[i] = fmaf(tv.x, wa, acc[i]);
            acc[i] = fmaf(tv.y, wb, acc[i]);
            acc[i] = fmaf(tv.z, wc, acc[i]);
            acc[i] = fmaf(tv.w, wd, acc[i]);
          }
        }
        #pragma unroll
        for (int i = 0; i < 4; ++i)
          unsafeAtomicAdd(&out1[(long)Edst[rg * 4 + i] * SD + 320 + j * 5 + K], PW2 * acc[i]);
      }
      __syncthreads();
    }
  }
}

extern "C" void kernel_launch(void* const* d_in, const int* in_sizes, int n_in,
                              void* d_out, int out_size, void* d_ws, size_t ws_size,
                              hipStream_t stream)
{
  const float* xs   = (const float*)d_in[0];
  const float* xsph = (const float*)d_in[1];
  const float* rbf  = (const float*)d_in[2];
  const float* rsh  = (const float*)d_in[3];
  const int*   ei   = (const int*)d_in[4];
  const float* lnw  = (const float*)d_in[5];
  const float* lnb  = (const float*)d_in[6];
  const float* o3w  = (const float*)d_in[7];
  const float* o3b  = (const float*)d_in[8];
  const float* w1   = (const float*)d_in[9];
  const float* b1   = (const float*)d_in[10];
  const float* w2   = (const float*)d_in[11];
  const float* b2   = (const float*)d_in[12];
  const float* rbfw = (const float*)d_in[13];
  const float* tpw  = (const float*)d_in[14];

  float* out0 = (float*)d_out;
  float* out1 = out0 + (size_t)NN * ND;

  float* ws      = (float*)d_ws;
  float* s_in    = ws;                            // 10000*128
  float* sph_in  = ws + (size_t)NN * ND;          // 10000*480
  float* s_out   = ws + (size_t)NN * (ND + SD);   // 10000*352

  node_ln_kernel<<<NN, 128, 0, stream>>>(xs, xsph, lnw, lnb, o3w, o3b, s_in, sph_in, out0, out1);
  mlp_kernel<<<NN / NPB, 256, 0, stream>>>(s_in, w1, b1, w2, b2, s_out);
  scalar_msg_kernel<<<NE / 2, 256, 0, stream>>>(rbf, rbfw, s_out, ei, out0);
  tp0_kernel<<<1250, 256, 0, stream>>>(rbf, rbfw, rsh, ei, s_out, sph_in, tpw, out1);
  tp1_kernel<<<1250, 256, 0, stream>>>(rbf, rbfw, rsh, ei, s_out, sph_in, tpw, out1);
  tp2_kernel<<<625, 256, 0, stream>>>(rbf, rbfw, rsh, ei, s_out, sph_in, tpw, out1);
}

// Round 2
// 1072.414 us; speedup vs baseline: 3.5514x; 3.5514x over previous
//
#include <hip/hip_runtime.h>

#define NN 10000
#define NE 100000
#define ND 128
#define NB 20
#define NIR 224
#define NH 352
#define SD 480
#define BS 512

// CG / normalization constants (verified in R1)
#define CR   0.70710678118654752f
#define CA   0.40824829046386302f
#define HA   0.20412414523193151f
#define HR   0.35355339059327376f
#define C110 0.57735026918962576f
#define C220 0.44721359549995794f
#define C111 0.40824829046386302f
#define C11X 0.44721359549995794f
#define C221 0.36514837167011074f
#define C222 0.58554004376912270f
#define S32  0.86602540378443865f
#define PW0  0.066815310478106094f
#define PW1  0.088388347648318447f
#define PW2  0.11918321088232916f

typedef __bf16 v8bf __attribute__((ext_vector_type(8)));
typedef unsigned short us8v __attribute__((ext_vector_type(8)));
typedef float f32x4 __attribute__((ext_vector_type(4)));

__device__ __forceinline__ unsigned short f2bf(float f) {
  unsigned int u = __builtin_bit_cast(unsigned int, f);
  u += 0x7fffu + ((u >> 16) & 1u);
  return (unsigned short)(u >> 16);
}
__device__ __forceinline__ float bf2f(unsigned short h) {
  unsigned int u = ((unsigned int)h) << 16;
  return __builtin_bit_cast(float, u);
}

__device__ __forceinline__ float warpReduceSum(float v) {
  #pragma unroll
  for (int off = 32; off > 0; off >>= 1) v += __shfl_down(v, off, 64);
  return v;
}

// ---------------- Kernel 1: scalar LN + O3 LN (unchanged, verified) ---------
__global__ __launch_bounds__(128) void node_ln_kernel(
    const float* __restrict__ xs, const float* __restrict__ xsph,
    const float* __restrict__ lnw, const float* __restrict__ lnb,
    const float* __restrict__ o3w, const float* __restrict__ o3b,
    float* __restrict__ s_in, float* __restrict__ sph_in,
    float* __restrict__ out0, float* __restrict__ out1)
{
  const int n = blockIdx.x, t = threadIdx.x;
  __shared__ float red[4];

  auto reduce2 = [&](float a, float b) {
    a = warpReduceSum(a); b = warpReduceSum(b);
    if ((t & 63) == 0) { red[(t >> 6) * 2] = a; red[(t >> 6) * 2 + 1] = b; }
    __syncthreads();
    float ra = red[0] + red[2], rb = red[1] + red[3];
    __syncthreads();
    return make_float2(ra, rb);
  };

  float x = xs[n * ND + t];
  float2 sr = reduce2(x, x * x);
  float mu = sr.x * (1.f / ND);
  float var = sr.y * (1.f / ND) - mu * mu;
  float y = (x - mu) * rsqrtf(var + 1e-5f) * lnw[t] + lnb[t];
  s_in[n * ND + t] = y; out0[n * ND + t] = y;

  float f = xsph[n * SD + t];
  float2 r0 = reduce2(f, f * f);
  float m0 = r0.x * (1.f / 128.f);
  float nrm0 = r0.y * (1.f / 128.f) - m0 * m0;
  float y0 = (f - m0) * rsqrtf(nrm0 + 1e-5f) * o3w[t] + o3b[t];
  sph_in[n * SD + t] = y0; out1[n * SD + t] = y0;

  float f1a = xsph[n * SD + 128 + t];
  float f1b = (t < 64) ? xsph[n * SD + 256 + t] : 0.f;
  float2 r1 = reduce2(f1a * f1a + f1b * f1b, 0.f);
  float rs1 = rsqrtf(r1.x * (1.f / 192.f) + 1e-5f);
  float ya = f1a * rs1 * o3w[128 + t / 3];
  sph_in[n * SD + 128 + t] = ya; out1[n * SD + 128 + t] = ya;
  if (t < 64) {
    float yb = f1b * rs1 * o3w[128 + (128 + t) / 3];
    sph_in[n * SD + 256 + t] = yb; out1[n * SD + 256 + t] = yb;
  }

  float f2a = xsph[n * SD + 320 + t];
  float f2b = (t < 32) ? xsph[n * SD + 448 + t] : 0.f;
  float2 r2 = reduce2(f2a * f2a + f2b * f2b, 0.f);
  float rs2 = rsqrtf(r2.x * (1.f / 160.f) + 1e-5f);
  float y2a = f2a * rs2 * o3w[192 + t / 5];
  sph_in[n * SD + 320 + t] = y2a; out1[n * SD + 320 + t] = y2a;
  if (t < 32) {
    float y2b = f2b * rs2 * o3w[192 + (128 + t) / 5];
    sph_in[n * SD + 448 + t] = y2b; out1[n * SD + 448 + t] = y2b;
  }
}

// ---------------- Kernel 2: node MLP (unchanged, verified) ------------------
#define NPB 8
__global__ __launch_bounds__(256) void mlp_kernel(
    const float* __restrict__ s_in, const float* __restrict__ w1,
    const float* __restrict__ b1, const float* __restrict__ w2,
    const float* __restrict__ b2, float* __restrict__ s_out)
{
  __shared__ float sIn[NPB][ND];
  __shared__ float sH[NPB][ND];
  const int t = threadIdx.x;
  const int n0 = blockIdx.x * NPB;
  for (int i = t; i < NPB * ND; i += 256) sIn[i >> 7][i & 127] = s_in[n0 * ND + i];
  __syncthreads();
  {
    const int j = t & 127, g = t >> 7;
    float acc[4] = {0.f, 0.f, 0.f, 0.f};
    for (int k = 0; k < ND; ++k) {
      float w = w1[k * ND + j];
      #pragma unroll
      for (int i = 0; i < 4; ++i) acc[i] = fmaf(sIn[g + 2 * i][k], w, acc[i]);
    }
    #pragma unroll
    for (int i = 0; i < 4; ++i) {
      float z = acc[i] + b1[j];
      sH[g + 2 * i][j] = z / (1.f + __expf(-z));
    }
  }
  __syncthreads();
  for (int jb = 0; jb < 2; ++jb) {
    int j = jb * 256 + t;
    if (j < NH) {
      float acc[NPB];
      #pragma unroll
      for (int i = 0; i < NPB; ++i) acc[i] = b2[j];
      for (int k = 0; k < ND; ++k) {
        float w = w2[k * NH + j];
        #pragma unroll
        for (int i = 0; i < NPB; ++i) acc[i] = fmaf(sH[i][k], w, acc[i]);
      }
      #pragma unroll
      for (int i = 0; i < NPB; ++i) s_out[(n0 + i) * NH + j] = acc[i];
    }
  }
}

// ---------------- W element fetchers (tpw fp32 layout, verified offsets) ----
__device__ __forceinline__ float wc0(const float* w, int u, int j) {
  int off = (u < 128) ? u * 128 : (u < 192) ? 16384 + (u - 128) * 128 : 24576 + (u - 192) * 128;
  return w[off + j];
}
__device__ __forceinline__ float wc1(const float* w, int u, int j) {
  int off = (u < 128) ? 28672 + u * 64 : (u < 192) ? 36864 + (u - 128) * 64
          : (u < 256) ? 40960 + (u - 192) * 64 : (u < 320) ? 45056 + (u - 256) * 64
          : (u < 352) ? 49152 + (u - 320) * 64 : 51200 + (u - 352) * 64;
  return w[off + j];
}
__device__ __forceinline__ float wc2(const float* w, int u, int j) {
  int off = (u < 128) ? 53248 + u * 32 : (u < 192) ? 57344 + (u - 128) * 32
          : (u < 256) ? 59392 + (u - 192) * 32 : (u < 288) ? 61440 + (u - 256) * 32
          : (u < 320) ? 62464 + (u - 288) * 32 : 63488 + (u - 320) * 32;
  return w[off + j];
}

// T-element emitter: tv[i] = sum_m cf[m] * x1vec[m][i], packed to bf16x8.
template<int M>
__device__ __forceinline__ void emit_dot(unsigned short* dst, const unsigned short* x1,
                                         const int* offs, const float* cf) {
  us8v xv[M];
  #pragma unroll
  for (int m = 0; m < M; ++m) xv[m] = *(const us8v*)&x1[offs[m]];
  us8v o;
  #pragma unroll
  for (int i = 0; i < 8; ++i) {
    float a = 0.f;
    #pragma unroll
    for (int m = 0; m < M; ++m) a = fmaf(cf[m], bf2f(xv[m][i]), a);
    o[i] = f2bf(a);
  }
  *(us8v*)dst = o;
}

// ---------------- T-slice builders (coeff form of R1-verified formulas) -----
// X1 layout (ushort bf16, row stride 488): [0..128) scalars; [128..320) l1 as
// [m][64 muls] (m=0..2); [320..480) l2 as [m][32 muls] (m=0..4).
#define TSTR 392

__device__ __forceinline__ void build0(unsigned short* Tb, const unsigned short* X1u,
                                       const float* RshF, int tid) {
  for (int it = tid; it < 32 * 28; it += BS) {
    int e = it / 28, ub = it - e * 28, u0 = ub * 8;
    const float* R = &RshF[e * 12];
    const unsigned short* x1 = &X1u[e * 488];
    unsigned short* dst = Tb + e * TSTR + u0;
    if (u0 < 128) {
      float cf[1] = { PW0 * R[0] };
      int offs[1] = { u0 };
      emit_dot<1>(dst, x1, offs, cf);
    } else if (u0 < 192) {
      int m0 = u0 - 128;
      float cf[3] = { PW0 * C110 * R[1], PW0 * C110 * R[2], PW0 * C110 * R[3] };
      int offs[3] = { 128 + m0, 192 + m0, 256 + m0 };
      emit_dot<3>(dst, x1, offs, cf);
    } else {
      int m0 = u0 - 192;
      float cf[5] = { PW0 * C220 * R[4], PW0 * C220 * R[5], PW0 * C220 * R[6],
                      PW0 * C220 * R[7], PW0 * C220 * R[8] };
      int offs[5] = { 320 + m0, 352 + m0, 384 + m0, 416 + m0, 448 + m0 };
      emit_dot<5>(dst, x1, offs, cf);
    }
  }
}

template<int k>
__device__ __forceinline__ void build1(unsigned short* Tb, const unsigned short* X1u,
                                       const float* RshF, int tid) {
  for (int it = tid; it < 32 * 48; it += BS) {
    int e = it / 48, ub = it - e * 48, u0 = ub * 8;
    const float* R = &RshF[e * 12];
    const unsigned short* x1 = &X1u[e * 488];
    unsigned short* dst = Tb + e * TSTR + u0;
    const float s = R[0], v0 = R[1], v1 = R[2], v2 = R[3];
    const float w0 = R[4], w1 = R[5], w2 = R[6], w3 = R[7], w4 = R[8];
    if (u0 < 128) {                 // (0,1,1)
      float cf[1] = { PW1 * C110 * R[1 + k] };
      int offs[1] = { u0 };
      emit_dot<1>(dst, x1, offs, cf);
    } else if (u0 < 192) {          // (1,0,1)
      float cf[1] = { PW1 * C110 * s };
      int offs[1] = { 128 + k * 64 + (u0 - 128) };
      emit_dot<1>(dst, x1, offs, cf);
    } else if (u0 < 256) {          // (1,1,1): b[ka]*v[kb] - b[kb]*v[ka]
      constexpr int ka = (k + 1) % 3, kb = (k + 2) % 3;
      int m0 = u0 - 192;
      float cf[2] = { PW1 * C111 * R[1 + kb], -PW1 * C111 * R[1 + ka] };
      int offs[2] = { 128 + ka * 64 + m0, 128 + kb * 64 + m0 };
      emit_dot<2>(dst, x1, offs, cf);
    } else if (u0 < 320) {          // (1,2,1)
      int m0 = u0 - 256;
      float cf[3];
      if constexpr (k == 0) { cf[0] = PW1*C11X*(-CA*w2 + CR*w4); cf[1] = PW1*C11X*CR*w0; cf[2] = PW1*C11X*CR*w3; }
      else if constexpr (k == 1) { cf[0] = PW1*C11X*CR*w0; cf[1] = PW1*C11X*(-CA*w2 - CR*w4); cf[2] = PW1*C11X*CR*w1; }
      else { cf[0] = PW1*C11X*CR*w3; cf[1] = PW1*C11X*CR*w1; cf[2] = PW1*C11X*2.f*CA*w2; }
      int offs[3] = { 128 + m0, 192 + m0, 256 + m0 };
      emit_dot<3>(dst, x1, offs, cf);
    } else if (u0 < 352) {          // (2,1,1)
      int m0 = u0 - 320;
      float cf[5];
      if constexpr (k == 0) { cf[0]=PW1*C11X*CR*v1; cf[1]=0.f; cf[2]=PW1*C11X*(-CA*v0); cf[3]=PW1*C11X*CR*v2; cf[4]=PW1*C11X*CR*v0; }
      else if constexpr (k == 1) { cf[0]=PW1*C11X*CR*v0; cf[1]=PW1*C11X*CR*v2; cf[2]=PW1*C11X*(-CA*v1); cf[3]=0.f; cf[4]=PW1*C11X*(-CR*v1); }
      else { cf[0]=0.f; cf[1]=PW1*C11X*CR*v1; cf[2]=PW1*C11X*2.f*CA*v2; cf[3]=PW1*C11X*CR*v0; cf[4]=0.f; }
      int offs[5] = { 320 + m0, 352 + m0, 384 + m0, 416 + m0, 448 + m0 };
      emit_dot<5>(dst, x1, offs, cf);
    } else {                        // (2,2,1)
      int m0 = u0 - 352;
      float cf[5];
      if constexpr (k == 0) { cf[0]=PW1*C221*0.5f*w3; cf[1]=PW1*C221*(S32*w2 + 0.5f*w4); cf[2]=PW1*C221*(-S32*w1); cf[3]=PW1*C221*(-0.5f*w0); cf[4]=PW1*C221*(-0.5f*w1); }
      else if constexpr (k == 1) { cf[0]=PW1*C221*(-0.5f*w1); cf[1]=PW1*C221*0.5f*w0; cf[2]=PW1*C221*S32*w3; cf[3]=PW1*C221*(-S32*w2 + 0.5f*w4); cf[4]=PW1*C221*(-0.5f*w3); }
      else { cf[0]=PW1*C221*(-w4); cf[1]=PW1*C221*(-0.5f*w3); cf[2]=0.f; cf[3]=PW1*C221*0.5f*w1; cf[4]=PW1*C221*w0; }
      int offs[5] = { 320 + m0, 352 + m0, 384 + m0, 416 + m0, 448 + m0 };
      emit_dot<5>(dst, x1, offs, cf);
    }
  }
}

template<int K>
__device__ __forceinline__ void build2(unsigned short* Tb, const unsigned short* X1u,
                                       const float* RshF, int tid) {
  for (int it = tid; it < 32 * 44; it += BS) {
    int e = it / 44, ub = it - e * 44, u0 = ub * 8;
    const float* R = &RshF[e * 12];
    const unsigned short* x1 = &X1u[e * 488];
    unsigned short* dst = Tb + e * TSTR + u0;
    const float s = R[0], v0 = R[1], v1 = R[2], v2 = R[3];
    const float w0 = R[4], w1 = R[5], w2 = R[6], w3 = R[7], w4 = R[8];
    if (u0 < 128) {                 // (0,2,2)
      float cf[1] = { PW2 * C220 * R[4 + K] };
      int offs[1] = { u0 };
      emit_dot<1>(dst, x1, offs, cf);
    } else if (u0 < 192) {          // (1,1,2)
      int m0 = u0 - 128;
      float cf[3];
      if constexpr (K == 0) { cf[0]=PW2*C11X*CR*v1; cf[1]=PW2*C11X*CR*v0; cf[2]=0.f; }
      else if constexpr (K == 1) { cf[0]=0.f; cf[1]=PW2*C11X*CR*v2; cf[2]=PW2*C11X*CR*v1; }
      else if constexpr (K == 2) { cf[0]=PW2*C11X*(-CA*v0); cf[1]=PW2*C11X*(-CA*v1); cf[2]=PW2*C11X*2.f*CA*v2; }
      else if constexpr (K == 3) { cf[0]=PW2*C11X*CR*v2; cf[1]=0.f; cf[2]=PW2*C11X*CR*v0; }
      else { cf[0]=PW2*C11X*CR*v0; cf[1]=PW2*C11X*(-CR*v1); cf[2]=0.f; }
      int offs[3] = { 128 + m0, 192 + m0, 256 + m0 };
      emit_dot<3>(dst, x1, offs, cf);
    } else if (u0 < 256) {          // (1,2,2)
      int m0 = u0 - 192;
      float cf[3];
      if constexpr (K == 0) { cf[0]=PW2*C221*(-0.5f*w3); cf[1]=PW2*C221*0.5f*w1; cf[2]=PW2*C221*w4; }
      else if constexpr (K == 1) { cf[0]=PW2*C221*(-S32*w2 - 0.5f*w4); cf[1]=PW2*C221*(-0.5f*w0); cf[2]=PW2*C221*0.5f*w3; }
      else if constexpr (K == 2) { cf[0]=PW2*C221*S32*w1; cf[1]=PW2*C221*(-S32*w3); cf[2]=0.f; }
      else if constexpr (K == 3) { cf[0]=PW2*C221*0.5f*w0; cf[1]=PW2*C221*(S32*w2 - 0.5f*w4); cf[2]=PW2*C221*(-0.5f*w1); }
      else { cf[0]=PW2*C221*0.5f*w1; cf[1]=PW2*C221*0.5f*w3; cf[2]=PW2*C221*(-w0); }
      int offs[3] = { 128 + m0, 192 + m0, 256 + m0 };
      emit_dot<3>(dst, x1, offs, cf);
    } else if (u0 < 288) {          // (2,0,2)
      int m0 = u0 - 256;
      float cf[1] = { PW2 * C220 * s };
      int offs[1] = { 320 + K * 32 + m0 };
      emit_dot<1>(dst, x1, offs, cf);
    } else if (u0 < 320) {          // (2,1,2)
      int m0 = u0 - 288;
      float cf[5];
      if constexpr (K == 0) { cf[0]=0.f; cf[1]=PW2*C221*0.5f*v1; cf[2]=0.f; cf[3]=PW2*C221*(-0.5f*v0); cf[4]=PW2*C221*v2; }
      else if constexpr (K == 1) { cf[0]=PW2*C221*(-0.5f*v1); cf[1]=0.f; cf[2]=PW2*C221*(-S32*v0); cf[3]=PW2*C221*0.5f*v2; cf[4]=PW2*C221*(-0.5f*v0); }
      else if constexpr (K == 2) { cf[0]=0.f; cf[1]=PW2*C221*S32*v0; cf[2]=0.f; cf[3]=PW2*C221*(-S32*v1); cf[4]=0.f; }
      else if constexpr (K == 3) { cf[0]=PW2*C221*0.5f*v0; cf[1]=PW2*C221*(-0.5f*v2); cf[2]=PW2*C221*S32*v1; cf[3]=0.f; cf[4]=PW2*C221*(-0.5f*v1); }
      else { cf[0]=PW2*C221*(-v2); cf[1]=PW2*C221*0.5f*v0; cf[2]=0.f; cf[3]=PW2*C221*0.5f*v1; cf[4]=0.f; }
      int offs[5] = { 320 + m0, 352 + m0, 384 + m0, 416 + m0, 448 + m0 };
      emit_dot<5>(dst, x1, offs, cf);
    } else {                        // (2,2,2)
      int m0 = u0 - 320;
      float cf[5];
      if constexpr (K == 0) { cf[0]=PW2*C222*(-CA*w2); cf[1]=PW2*C222*HR*w3; cf[2]=PW2*C222*(-CA*w0); cf[3]=PW2*C222*HR*w1; cf[4]=0.f; }
      else if constexpr (K == 1) { cf[0]=PW2*C222*HR*w3; cf[1]=PW2*C222*(HA*w2 - HR*w4); cf[2]=PW2*C222*HA*w1; cf[3]=PW2*C222*HR*w0; cf[4]=PW2*C222*(-HR*w1); }
      else if constexpr (K == 2) { cf[0]=PW2*C222*(-CA*w0); cf[1]=PW2*C222*HA*w1; cf[2]=PW2*C222*CA*w2; cf[3]=PW2*C222*HA*w3; cf[4]=PW2*C222*(-CA*w4); }
      else if constexpr (K == 3) { cf[0]=PW2*C222*HR*w1; cf[1]=PW2*C222*HR*w0; cf[2]=PW2*C222*HA*w3; cf[3]=PW2*C222*(HA*w2 + HR*w4); cf[4]=PW2*C222*HR*w3; }
      else { cf[0]=0.f; cf[1]=PW2*C222*(-HR*w1); cf[2]=PW2*C222*(-CA*w4); cf[3]=PW2*C222*HR*w3; cf[4]=PW2*C222*(-CA*w2); }
      int offs[5] = { 320 + m0, 352 + m0, 384 + m0, 416 + m0, 448 + m0 };
      emit_dot<5>(dst, x1, offs, cf);
    }
  }
}

// ---------------- Fused TP kernel --------------------------------------------
// LDS map (bytes):
//   [0, 25088)      Tbuf0        (32 x 392 ushort)
//   [25088, 50176)  Tbuf1
//   gate (fp32 32x228 = 29184) aliases [0, 29184)   (dead before Tbuf writes)
//   rbfpad (ushort 32x40 = 2560) at [29184, 31744)  (dead before Tbuf1 writes)
//   [50176, 81408)  X1 (ushort 32x488)
//   [81408, 82944)  Rsh (fp32 32x12)
//   [82944, 83072)  Edst; [83072, 83200) Esrc
__global__ __launch_bounds__(BS, 2) void tp_fused_kernel(
    const float* __restrict__ rbf, const float* __restrict__ rbf_w,
    const float* __restrict__ rsh, const int* __restrict__ ei,
    const float* __restrict__ s_out, const float* __restrict__ sph_in,
    const float* __restrict__ tpw, float* __restrict__ out0,
    float* __restrict__ out1)
{
  __shared__ __align__(16) unsigned char smem[83200];
  unsigned short* Tb0 = (unsigned short*)smem;
  unsigned short* Tb1 = (unsigned short*)(smem + 25088);
  float* gateF = (float*)smem;
  unsigned short* rbfpadU = (unsigned short*)(smem + 29184);
  unsigned short* X1u = (unsigned short*)(smem + 50176);
  float* RshF = (float*)(smem + 81408);
  int* EdstS = (int*)(smem + 82944);
  int* EsrcS = (int*)(smem + 83072);

  const int tid = threadIdx.x;
  const int wid = tid >> 6, lane = tid & 63;
  const int r = lane & 15, kl = lane >> 4;

  // ---- Preload W B-fragments into registers (constant across tiles) ----
  v8bf bw0[7], bw1[12], bw2[6], bfq[6];
  #pragma unroll
  for (int kk = 0; kk < 7; ++kk) {
    us8v v;
    #pragma unroll
    for (int i = 0; i < 8; ++i) v[i] = f2bf(wc0(tpw, kk * 32 + kl * 8 + i, wid * 16 + r));
    bw0[kk] = __builtin_bit_cast(v8bf, v);
  }
  #pragma unroll
  for (int kk = 0; kk < 12; ++kk) {
    us8v v;
    #pragma unroll
    for (int i = 0; i < 8; ++i) v[i] = f2bf(wc1(tpw, kk * 32 + kl * 8 + i, (wid & 3) * 16 + r));
    bw1[kk] = __builtin_bit_cast(v8bf, v);
  }
  {
    const int kh = wid >> 2;
    #pragma unroll
    for (int q = 0; q < 6; ++q) {
      us8v v;
      int kk = kh * 6 + q;
      #pragma unroll
      for (int i = 0; i < 8; ++i)
        v[i] = (kk < 11) ? f2bf(wc2(tpw, kk * 32 + kl * 8 + i, (wid & 1) * 16 + r)) : (unsigned short)0;
      bw2[q] = __builtin_bit_cast(v8bf, v);
    }
  }
  #pragma unroll
  for (int q = 0; q < 6; ++q) {
    us8v v;
    int t44 = wid + q * 8;
    int nt = t44 >> 1;
    #pragma unroll
    for (int i = 0; i < 8; ++i) {
      int k = kl * 8 + i;
      v[i] = (t44 < 44 && k < 20) ? f2bf(rbf_w[k * NH + nt * 16 + r]) : (unsigned short)0;
    }
    bfq[q] = __builtin_bit_cast(v8bf, v);
  }

  auto MFMA = [](v8bf a, v8bf b, f32x4 c) {
    return __builtin_amdgcn_mfma_f32_16x16x32_bf16(a, b, c, 0, 0, 0);
  };

  auto mfma_l0 = [&](const unsigned short* T) {
    f32x4 acc0 = {0.f, 0.f, 0.f, 0.f}, acc1 = {0.f, 0.f, 0.f, 0.f};
    const unsigned short* p0 = T + r * TSTR + kl * 8;
    const unsigned short* p1 = T + (16 + r) * TSTR + kl * 8;
    #pragma unroll
    for (int kk = 0; kk < 7; ++kk) {
      us8v a0 = *(const us8v*)(p0 + kk * 32);
      us8v a1 = *(const us8v*)(p1 + kk * 32);
      acc0 = MFMA(__builtin_bit_cast(v8bf, a0), bw0[kk], acc0);
      acc1 = MFMA(__builtin_bit_cast(v8bf, a1), bw0[kk], acc1);
    }
    int col = wid * 16 + r;
    #pragma unroll
    for (int j = 0; j < 4; ++j) {
      unsafeAtomicAdd(&out1[(long)EdstS[kl * 4 + j] * SD + col], acc0[j]);
      unsafeAtomicAdd(&out1[(long)EdstS[16 + kl * 4 + j] * SD + col], acc1[j]);
    }
  };

  auto mfma_l1 = [&](const unsigned short* T, int k) {
    const int mt = wid >> 2, nt = wid & 3;
    f32x4 acc = {0.f, 0.f, 0.f, 0.f};
    const unsigned short* p = T + (mt * 16 + r) * TSTR + kl * 8;
    #pragma unroll
    for (int kk = 0; kk < 12; ++kk) {
      us8v a = *(const us8v*)(p + kk * 32);
      acc = MFMA(__builtin_bit_cast(v8bf, a), bw1[kk], acc);
    }
    int col = 128 + (nt * 16 + r) * 3 + k;
    #pragma unroll
    for (int j = 0; j < 4; ++j)
      unsafeAtomicAdd(&out1[(long)EdstS[mt * 16 + kl * 4 + j] * SD + col], acc[j]);
  };

  auto mfma_l2 = [&](const unsigned short* T, int K) {
    const int kh = wid >> 2, mt = (wid >> 1) & 1, ntc = wid & 1;
    f32x4 acc = {0.f, 0.f, 0.f, 0.f};
    const unsigned short* p = T + (mt * 16 + r) * TSTR + kl * 8 + kh * 192;
    #pragma unroll
    for (int q = 0; q < 6; ++q) {
      if (kh == 0 || q < 5) {
        us8v a = *(const us8v*)(p + q * 32);
        acc = MFMA(__builtin_bit_cast(v8bf, a), bw2[q], acc);
      }
    }
    int col = 320 + (ntc * 16 + r) * 5 + K;
    #pragma unroll
    for (int j = 0; j < 4; ++j)
      unsafeAtomicAdd(&out1[(long)EdstS[mt * 16 + kl * 4 + j] * SD + col], acc[j]);
  };

  for (int tile = blockIdx.x; tile < NE / 32; tile += gridDim.x) {
    const int e0 = tile * 32;
    // ---- stage ----
    for (int i = tid; i < 32; i += BS) { EdstS[i] = ei[e0 + i]; EsrcS[i] = ei[NE + e0 + i]; }
    for (int i = tid; i < 288; i += BS) RshF[(i / 9) * 12 + (i % 9)] = rsh[(long)e0 * 9 + i];
    for (int i = tid; i < 1024; i += BS) {
      int e = i >> 5, b = i & 31;
      rbfpadU[e * 40 + b] = (b < 20) ? f2bf(rbf[(long)(e0 + e) * NB + b]) : (unsigned short)0;
    }
    __syncthreads();
    // ---- filt MFMA -> gate (LDS) + scalar msg (atomics) ----
    {
      us8v ra0 = *(const us8v*)&rbfpadU[r * 40 + kl * 8];
      us8v ra1 = *(const us8v*)&rbfpadU[(16 + r) * 40 + kl * 8];
      v8bf av0 = __builtin_bit_cast(v8bf, ra0);
      v8bf av1 = __builtin_bit_cast(v8bf, ra1);
      #pragma unroll
      for (int q = 0; q < 6; ++q) {
        int t44 = wid + q * 8;
        if (t44 < 44) {
          int mt = t44 & 1, nt = t44 >> 1;
          f32x4 acc = {0.f, 0.f, 0.f, 0.f};
          acc = MFMA(mt ? av1 : av0, bfq[q], acc);
          int gi = nt * 16 + r;
          #pragma unroll
          for (int j = 0; j < 4; ++j) {
            int e = mt * 16 + kl * 4 + j;
            float so = s_out[(long)EsrcS[e] * NH + gi];
            float val = acc[j] * so;
            if (nt < 14) gateF[e * 228 + gi] = val;
            else unsafeAtomicAdd(&out0[(long)EdstS[e] * ND + (gi - 224)], val);
          }
        }
      }
    }
    __syncthreads();
    // ---- X1 build (bf16, l1/l2 sections component-transposed) ----
    for (int it = tid; it < 1920; it += BS) {
      int e = it / 60, cb = it - e * 60, c0 = cb * 8;
      const float* gp = &gateF[e * 228];
      long srow = (long)EsrcS[e] * SD;
      us8v o;
      if (c0 < 128) {
        const float4 sa = *(const float4*)&sph_in[srow + c0];
        const float4 sb = *(const float4*)&sph_in[srow + c0 + 4];
        float sv[8] = {sa.x, sa.y, sa.z, sa.w, sb.x, sb.y, sb.z, sb.w};
        #pragma unroll
        for (int i = 0; i < 8; ++i) o[i] = f2bf(sv[i] * gp[c0 + i]);
      } else if (c0 < 320) {
        int m = (c0 - 128) >> 6, mul0 = (c0 - 128) & 63;
        #pragma unroll
        for (int i = 0; i < 8; ++i) {
          int mul = mul0 + i;
          o[i] = f2bf(sph_in[srow + 128 + mul * 3 + m] * gp[128 + mul]);
        }
      } else {
        int m = (c0 - 320) >> 5, mul0 = (c0 - 320) & 31;
        #pragma unroll
        for (int i = 0; i < 8; ++i) {
          int mul = mul0 + i;
          o[i] = f2bf(sph_in[srow + 320 + mul * 5 + m] * gp[192 + mul]);
        }
      }
      *(us8v*)&X1u[e * 488 + c0] = o;
    }
    __syncthreads();
    // ---- 9 phases, double-buffered T ----
    build0(Tb0, X1u, RshF, tid); __syncthreads();
    build1<0>(Tb1, X1u, RshF, tid); mfma_l0(Tb0); __syncthreads();
    build1<1>(Tb0, X1u, RshF, tid); mfma_l1(Tb1, 0); __syncthreads();
    build1<2>(Tb1, X1u, RshF, tid); mfma_l1(Tb0, 1); __syncthreads();
    build2<0>(Tb0, X1u, RshF, tid); mfma_l1(Tb1, 2); __syncthreads();
    build2<1>(Tb1, X1u, RshF, tid); mfma_l2(Tb0, 0); __syncthreads();
    build2<2>(Tb0, X1u, RshF, tid); mfma_l2(Tb1, 1); __syncthreads();
    build2<3>(Tb1, X1u, RshF, tid); mfma_l2(Tb0, 2); __syncthreads();
    build2<4>(Tb0, X1u, RshF, tid); mfma_l2(Tb1, 3); __syncthreads();
    mfma_l2(Tb0, 4); __syncthreads();
  }
}

extern "C" void kernel_launch(void* const* d_in, const int* in_sizes, int n_in,
                              void* d_out, int out_size, void* d_ws, size_t ws_size,
                              hipStream_t stream)
{
  const float* xs   = (const float*)d_in[0];
  const float* xsph = (const float*)d_in[1];
  const float* rbf  = (const float*)d_in[2];
  const float* rsh  = (const float*)d_in[3];
  const int*   ei   = (const int*)d_in[4];
  const float* lnw  = (const float*)d_in[5];
  const float* lnb  = (const float*)d_in[6];
  const float* o3w  = (const float*)d_in[7];
  const float* o3b  = (const float*)d_in[8];
  const float* w1   = (const float*)d_in[9];
  const float* b1   = (const float*)d_in[10];
  const float* w2   = (const float*)d_in[11];
  const float* b2   = (const float*)d_in[12];
  const float* rbfw = (const float*)d_in[13];
  const float* tpw  = (const float*)d_in[14];

  float* out0 = (float*)d_out;
  float* out1 = out0 + (size_t)NN * ND;

  float* ws      = (float*)d_ws;
  float* s_in    = ws;                            // 10000*128
  float* sph_in  = ws + (size_t)NN * ND;          // 10000*480
  float* s_out   = ws + (size_t)NN * (ND + SD);   // 10000*352

  node_ln_kernel<<<NN, 128, 0, stream>>>(xs, xsph, lnw, lnb, o3w, o3b, s_in, sph_in, out0, out1);
  mlp_kernel<<<NN / NPB, 256, 0, stream>>>(s_in, w1, b1, w2, b2, s_out);
  tp_fused_kernel<<<256, BS, 0, stream>>>(rbf, rbfw, rsh, ei, s_out, sph_in, tpw, out0, out1);
}

// Round 3
// 1014.259 us; speedup vs baseline: 3.7550x; 1.0573x over previous
//
#include <hip/hip_runtime.h>

#define NN 10000
#define NE 100000
#define ND 128
#define NB 20
#define NIR 224
#define NH 352
#define SD 480
#define BS 512

// CG / normalization constants (verified in R1/R2)
#define CR   0.70710678118654752f
#define CA   0.40824829046386302f
#define HA   0.20412414523193151f
#define HR   0.35355339059327376f
#define C110 0.57735026918962576f
#define C220 0.44721359549995794f
#define C111 0.40824829046386302f
#define C11X 0.44721359549995794f
#define C221 0.36514837167011074f
#define C222 0.58554004376912270f
#define S32  0.86602540378443865f
#define PW0  0.066815310478106094f
#define PW1  0.088388347648318447f
#define PW2  0.11918321088232916f

typedef __bf16 v8bf __attribute__((ext_vector_type(8)));
typedef unsigned short us8v __attribute__((ext_vector_type(8)));
typedef float f32x4 __attribute__((ext_vector_type(4)));

__device__ __forceinline__ unsigned short f2bfc(float f) {
  __bf16 h = (__bf16)f;
  return __builtin_bit_cast(unsigned short, h);
}
__device__ __forceinline__ float bf2f(unsigned short h) {
  unsigned int u = ((unsigned int)h) << 16;
  return __builtin_bit_cast(float, u);
}

__device__ __forceinline__ float warpReduceSum(float v) {
  #pragma unroll
  for (int off = 32; off > 0; off >>= 1) v += __shfl_down(v, off, 64);
  return v;
}

// ---------------- Kernel 1: scalar LN + O3 LN (unchanged, verified) ---------
__global__ __launch_bounds__(128) void node_ln_kernel(
    const float* __restrict__ xs, const float* __restrict__ xsph,
    const float* __restrict__ lnw, const float* __restrict__ lnb,
    const float* __restrict__ o3w, const float* __restrict__ o3b,
    float* __restrict__ s_in, float* __restrict__ sph_in,
    float* __restrict__ out0, float* __restrict__ out1)
{
  const int n = blockIdx.x, t = threadIdx.x;
  __shared__ float red[4];

  auto reduce2 = [&](float a, float b) {
    a = warpReduceSum(a); b = warpReduceSum(b);
    if ((t & 63) == 0) { red[(t >> 6) * 2] = a; red[(t >> 6) * 2 + 1] = b; }
    __syncthreads();
    float ra = red[0] + red[2], rb = red[1] + red[3];
    __syncthreads();
    return make_float2(ra, rb);
  };

  float x = xs[n * ND + t];
  float2 sr = reduce2(x, x * x);
  float mu = sr.x * (1.f / ND);
  float var = sr.y * (1.f / ND) - mu * mu;
  float y = (x - mu) * rsqrtf(var + 1e-5f) * lnw[t] + lnb[t];
  s_in[n * ND + t] = y; out0[n * ND + t] = y;

  float f = xsph[n * SD + t];
  float2 r0 = reduce2(f, f * f);
  float m0 = r0.x * (1.f / 128.f);
  float nrm0 = r0.y * (1.f / 128.f) - m0 * m0;
  float y0 = (f - m0) * rsqrtf(nrm0 + 1e-5f) * o3w[t] + o3b[t];
  sph_in[n * SD + t] = y0; out1[n * SD + t] = y0;

  float f1a = xsph[n * SD + 128 + t];
  float f1b = (t < 64) ? xsph[n * SD + 256 + t] : 0.f;
  float2 r1 = reduce2(f1a * f1a + f1b * f1b, 0.f);
  float rs1 = rsqrtf(r1.x * (1.f / 192.f) + 1e-5f);
  float ya = f1a * rs1 * o3w[128 + t / 3];
  sph_in[n * SD + 128 + t] = ya; out1[n * SD + 128 + t] = ya;
  if (t < 64) {
    float yb = f1b * rs1 * o3w[128 + (128 + t) / 3];
    sph_in[n * SD + 256 + t] = yb; out1[n * SD + 256 + t] = yb;
  }

  float f2a = xsph[n * SD + 320 + t];
  float f2b = (t < 32) ? xsph[n * SD + 448 + t] : 0.f;
  float2 r2 = reduce2(f2a * f2a + f2b * f2b, 0.f);
  float rs2 = rsqrtf(r2.x * (1.f / 160.f) + 1e-5f);
  float y2a = f2a * rs2 * o3w[192 + t / 5];
  sph_in[n * SD + 320 + t] = y2a; out1[n * SD + 320 + t] = y2a;
  if (t < 32) {
    float y2b = f2b * rs2 * o3w[192 + (128 + t) / 5];
    sph_in[n * SD + 448 + t] = y2b; out1[n * SD + 448 + t] = y2b;
  }
}

// ---------------- Kernel 2: node MLP (unchanged, verified) ------------------
#define NPB 8
__global__ __launch_bounds__(256) void mlp_kernel(
    const float* __restrict__ s_in, const float* __restrict__ w1,
    const float* __restrict__ b1, const float* __restrict__ w2,
    const float* __restrict__ b2, float* __restrict__ s_out)
{
  __shared__ float sIn[NPB][ND];
  __shared__ float sH[NPB][ND];
  const int t = threadIdx.x;
  const int n0 = blockIdx.x * NPB;
  for (int i = t; i < NPB * ND; i += 256) sIn[i >> 7][i & 127] = s_in[n0 * ND + i];
  __syncthreads();
  {
    const int j = t & 127, g = t >> 7;
    float acc[4] = {0.f, 0.f, 0.f, 0.f};
    for (int k = 0; k < ND; ++k) {
      float w = w1[k * ND + j];
      #pragma unroll
      for (int i = 0; i < 4; ++i) acc[i] = fmaf(sIn[g + 2 * i][k], w, acc[i]);
    }
    #pragma unroll
    for (int i = 0; i < 4; ++i) {
      float z = acc[i] + b1[j];
      sH[g + 2 * i][j] = z / (1.f + __expf(-z));
    }
  }
  __syncthreads();
  for (int jb = 0; jb < 2; ++jb) {
    int j = jb * 256 + t;
    if (j < NH) {
      float acc[NPB];
      #pragma unroll
      for (int i = 0; i < NPB; ++i) acc[i] = b2[j];
      for (int k = 0; k < ND; ++k) {
        float w = w2[k * NH + j];
        #pragma unroll
        for (int i = 0; i < NPB; ++i) acc[i] = fmaf(sH[i][k], w, acc[i]);
      }
      #pragma unroll
      for (int i = 0; i < NPB; ++i) s_out[(n0 + i) * NH + j] = acc[i];
    }
  }
}

// ---------------- W element fetchers (tpw fp32 layout, verified offsets) ----
__device__ __forceinline__ float wc0(const float* w, int u, int j) {
  int off = (u < 128) ? u * 128 : (u < 192) ? 16384 + (u - 128) * 128 : 24576 + (u - 192) * 128;
  return w[off + j];
}
__device__ __forceinline__ float wc1(const float* w, int u, int j) {
  int off = (u < 128) ? 28672 + u * 64 : (u < 192) ? 36864 + (u - 128) * 64
          : (u < 256) ? 40960 + (u - 192) * 64 : (u < 320) ? 45056 + (u - 256) * 64
          : (u < 352) ? 49152 + (u - 320) * 64 : 51200 + (u - 352) * 64;
  return w[off + j];
}
__device__ __forceinline__ float wc2(const float* w, int u, int j) {
  int off = (u < 128) ? 53248 + u * 32 : (u < 192) ? 57344 + (u - 128) * 32
          : (u < 256) ? 59392 + (u - 192) * 32 : (u < 288) ? 61440 + (u - 256) * 32
          : (u < 320) ? 62464 + (u - 288) * 32 : 63488 + (u - 320) * 32;
  return w[off + j];
}

// ---------------- Prep kernel: pre-swizzle W into bf16 fragment layout ------
// W0g: 7*8*512,  W1g: 12*4*512,  W2g: 6*2*2*512,  Wfq: 6*8*512  (ushorts)
__global__ __launch_bounds__(256) void prep_w_kernel(
    const float* __restrict__ tpw, const float* __restrict__ rbf_w,
    unsigned short* __restrict__ W0g, unsigned short* __restrict__ W1g,
    unsigned short* __restrict__ W2g, unsigned short* __restrict__ Wfq)
{
  int gid = blockIdx.x * 256 + threadIdx.x;
  int i = gid & 7, lane = (gid >> 3) & 63;
  int r = lane & 15, kl = lane >> 4;
  if (gid < 28672) {
    int fid = gid >> 9, kk = fid >> 3, wid = fid & 7;
    W0g[gid] = f2bfc(wc0(tpw, kk * 32 + kl * 8 + i, wid * 16 + r));
  } else if (gid < 53248) {
    int g = gid - 28672, fid = g >> 9, kk = fid >> 2, nt = fid & 3;
    W1g[g] = f2bfc(wc1(tpw, kk * 32 + kl * 8 + i, nt * 16 + r));
  } else if (gid < 65536) {
    int g = gid - 53248, fid = g >> 9, q = fid >> 2, kh = (fid >> 1) & 1, ntc = fid & 1;
    int kk = kh * 6 + q;
    W2g[g] = (kk < 11) ? f2bfc(wc2(tpw, kk * 32 + kl * 8 + i, ntc * 16 + r)) : (unsigned short)0;
  } else if (gid < 90112) {
    int g = gid - 65536, fid = g >> 9, q = fid >> 3, wid = fid & 7;
    int t44 = wid + q * 8, nt = t44 >> 1, k = kl * 8 + i;
    Wfq[g] = (t44 < 44 && k < 20) ? f2bfc(rbf_w[k * NH + nt * 16 + r]) : (unsigned short)0;
  }
}

// T-element emitter: tv[i] = sum_m cf[m] * x1vec[m][i], packed to bf16x8.
template<int M>
__device__ __forceinline__ void emit_dot(unsigned short* dst, const unsigned short* x1,
                                         const int* offs, const float* cf) {
  us8v xv[M];
  #pragma unroll
  for (int m = 0; m < M; ++m) xv[m] = *(const us8v*)&x1[offs[m]];
  v8bf o;
  #pragma unroll
  for (int i = 0; i < 8; ++i) {
    float a = 0.f;
    #pragma unroll
    for (int m = 0; m < M; ++m) a = fmaf(cf[m], bf2f(xv[m][i]), a);
    o[i] = (__bf16)a;
  }
  *(us8v*)dst = __builtin_bit_cast(us8v, o);
}

// ---------------- T-slice builders ------------------------------------------
// X1 layout (ushort bf16, row stride 480): [0..128) scalars; [128..320) l1 as
// [m][64 muls]; [320..480) l2 as [m][32 muls].
// Tb: row stride 384 ushorts + XOR swizzle idx ^= (e&7)<<3.
#define TSW(e, idx) ((idx) ^ (((e) & 7) << 3))

__device__ __forceinline__ void build0(unsigned short* Tb, const unsigned short* X1u,
                                       const float* RshF, int tid) {
  for (int it = tid; it < 32 * 28; it += BS) {
    int e = it / 28, ub = it - e * 28, u0 = ub * 8;
    const float* R = &RshF[e * 9];
    const unsigned short* x1 = &X1u[e * 480];
    unsigned short* dst = Tb + TSW(e, e * 384 + u0);
    if (u0 < 128) {
      float cf[1] = { PW0 * R[0] };
      int offs[1] = { u0 };
      emit_dot<1>(dst, x1, offs, cf);
    } else if (u0 < 192) {
      int m0 = u0 - 128;
      float cf[3] = { PW0 * C110 * R[1], PW0 * C110 * R[2], PW0 * C110 * R[3] };
      int offs[3] = { 128 + m0, 192 + m0, 256 + m0 };
      emit_dot<3>(dst, x1, offs, cf);
    } else {
      int m0 = u0 - 192;
      float cf[5] = { PW0 * C220 * R[4], PW0 * C220 * R[5], PW0 * C220 * R[6],
                      PW0 * C220 * R[7], PW0 * C220 * R[8] };
      int offs[5] = { 320 + m0, 352 + m0, 384 + m0, 416 + m0, 448 + m0 };
      emit_dot<5>(dst, x1, offs, cf);
    }
  }
}

template<int k>
__device__ __forceinline__ void build1(unsigned short* Tb, const unsigned short* X1u,
                                       const float* RshF, int tid) {
  for (int it = tid; it < 32 * 48; it += BS) {
    int e = it / 48, ub = it - e * 48, u0 = ub * 8;
    const float* R = &RshF[e * 9];
    const unsigned short* x1 = &X1u[e * 480];
    unsigned short* dst = Tb + TSW(e, e * 384 + u0);
    const float s = R[0], v0 = R[1], v1 = R[2], v2 = R[3];
    const float w0 = R[4], w1 = R[5], w2 = R[6], w3 = R[7], w4 = R[8];
    if (u0 < 128) {                 // (0,1,1)
      float cf[1] = { PW1 * C110 * R[1 + k] };
      int offs[1] = { u0 };
      emit_dot<1>(dst, x1, offs, cf);
    } else if (u0 < 192) {          // (1,0,1)
      float cf[1] = { PW1 * C110 * s };
      int offs[1] = { 128 + k * 64 + (u0 - 128) };
      emit_dot<1>(dst, x1, offs, cf);
    } else if (u0 < 256) {          // (1,1,1)
      constexpr int ka = (k + 1) % 3, kb = (k + 2) % 3;
      int m0 = u0 - 192;
      float cf[2] = { PW1 * C111 * R[1 + kb], -PW1 * C111 * R[1 + ka] };
      int offs[2] = { 128 + ka * 64 + m0, 128 + kb * 64 + m0 };
      emit_dot<2>(dst, x1, offs, cf);
    } else if (u0 < 320) {          // (1,2,1)
      int m0 = u0 - 256;
      float cf[3];
      if constexpr (k == 0) { cf[0] = PW1*C11X*(-CA*w2 + CR*w4); cf[1] = PW1*C11X*CR*w0; cf[2] = PW1*C11X*CR*w3; }
      else if constexpr (k == 1) { cf[0] = PW1*C11X*CR*w0; cf[1] = PW1*C11X*(-CA*w2 - CR*w4); cf[2] = PW1*C11X*CR*w1; }
      else { cf[0] = PW1*C11X*CR*w3; cf[1] = PW1*C11X*CR*w1; cf[2] = PW1*C11X*2.f*CA*w2; }
      int offs[3] = { 128 + m0, 192 + m0, 256 + m0 };
      emit_dot<3>(dst, x1, offs, cf);
    } else if (u0 < 352) {          // (2,1,1) zero-pruned
      int m0 = u0 - 320;
      if constexpr (k == 0) {
        float cf[4] = { PW1*C11X*CR*v1, PW1*C11X*(-CA*v0), PW1*C11X*CR*v2, PW1*C11X*CR*v0 };
        int offs[4] = { 320 + m0, 384 + m0, 416 + m0, 448 + m0 };
        emit_dot<4>(dst, x1, offs, cf);
      } else if constexpr (k == 1) {
        float cf[4] = { PW1*C11X*CR*v0, PW1*C11X*CR*v2, PW1*C11X*(-CA*v1), PW1*C11X*(-CR*v1) };
        int offs[4] = { 320 + m0, 352 + m0, 384 + m0, 448 + m0 };
        emit_dot<4>(dst, x1, offs, cf);
      } else {
        float cf[3] = { PW1*C11X*CR*v1, PW1*C11X*2.f*CA*v2, PW1*C11X*CR*v0 };
        int offs[3] = { 352 + m0, 384 + m0, 416 + m0 };
        emit_dot<3>(dst, x1, offs, cf);
      }
    } else {                        // (2,2,1) zero-pruned
      int m0 = u0 - 352;
      if constexpr (k == 0) {
        float cf[5] = { PW1*C221*0.5f*w3, PW1*C221*(S32*w2 + 0.5f*w4), PW1*C221*(-S32*w1),
                        PW1*C221*(-0.5f*w0), PW1*C221*(-0.5f*w1) };
        int offs[5] = { 320 + m0, 352 + m0, 384 + m0, 416 + m0, 448 + m0 };
        emit_dot<5>(dst, x1, offs, cf);
      } else if constexpr (k == 1) {
        float cf[5] = { PW1*C221*(-0.5f*w1), PW1*C221*0.5f*w0, PW1*C221*S32*w3,
                        PW1*C221*(-S32*w2 + 0.5f*w4), PW1*C221*(-0.5f*w3) };
        int offs[5] = { 320 + m0, 352 + m0, 384 + m0, 416 + m0, 448 + m0 };
        emit_dot<5>(dst, x1, offs, cf);
      } else {
        float cf[4] = { PW1*C221*(-w4), PW1*C221*(-0.5f*w3), PW1*C221*0.5f*w1, PW1*C221*w0 };
        int offs[4] = { 320 + m0, 352 + m0, 416 + m0, 448 + m0 };
        emit_dot<4>(dst, x1, offs, cf);
      }
    }
  }
}

template<int K>
__device__ __forceinline__ void build2(unsigned short* Tb, const unsigned short* X1u,
                                       const float* RshF, int tid) {
  for (int it = tid; it < 32 * 44; it += BS) {
    int e = it / 44, ub = it - e * 44, u0 = ub * 8;
    const float* R = &RshF[e * 9];
    const unsigned short* x1 = &X1u[e * 480];
    unsigned short* dst = Tb + TSW(e, e * 384 + u0);
    const float s = R[0], v0 = R[1], v1 = R[2], v2 = R[3];
    const float w0 = R[4], w1 = R[5], w2 = R[6], w3 = R[7], w4 = R[8];
    if (u0 < 128) {                 // (0,2,2)
      float cf[1] = { PW2 * C220 * R[4 + K] };
      int offs[1] = { u0 };
      emit_dot<1>(dst, x1, offs, cf);
    } else if (u0 < 192) {          // (1,1,2) zero-pruned
      int m0 = u0 - 128;
      if constexpr (K == 0) {
        float cf[2] = { PW2*C11X*CR*v1, PW2*C11X*CR*v0 };
        int offs[2] = { 128 + m0, 192 + m0 };
        emit_dot<2>(dst, x1, offs, cf);
      } else if constexpr (K == 1) {
        float cf[2] = { PW2*C11X*CR*v2, PW2*C11X*CR*v1 };
        int offs[2] = { 192 + m0, 256 + m0 };
        emit_dot<2>(dst, x1, offs, cf);
      } else if constexpr (K == 2) {
        float cf[3] = { PW2*C11X*(-CA*v0), PW2*C11X*(-CA*v1), PW2*C11X*2.f*CA*v2 };
        int offs[3] = { 128 + m0, 192 + m0, 256 + m0 };
        emit_dot<3>(dst, x1, offs, cf);
      } else if constexpr (K == 3) {
        float cf[2] = { PW2*C11X*CR*v2, PW2*C11X*CR*v0 };
        int offs[2] = { 128 + m0, 256 + m0 };
        emit_dot<2>(dst, x1, offs, cf);
      } else {
        float cf[2] = { PW2*C11X*CR*v0, PW2*C11X*(-CR*v1) };
        int offs[2] = { 128 + m0, 192 + m0 };
        emit_dot<2>(dst, x1, offs, cf);
      }
    } else if (u0 < 256) {          // (1,2,2) zero-pruned
      int m0 = u0 - 192;
      if constexpr (K == 2) {
        float cf[2] = { PW2*C221*S32*w1, PW2*C221*(-S32*w3) };
        int offs[2] = { 128 + m0, 192 + m0 };
        emit_dot<2>(dst, x1, offs, cf);
      } else {
        float cf[3];
        if constexpr (K == 0) { cf[0]=PW2*C221*(-0.5f*w3); cf[1]=PW2*C221*0.5f*w1; cf[2]=PW2*C221*w4; }
        else if constexpr (K == 1) { cf[0]=PW2*C221*(-S32*w2 - 0.5f*w4); cf[1]=PW2*C221*(-0.5f*w0); cf[2]=PW2*C221*0.5f*w3; }
        else if constexpr (K == 3) { cf[0]=PW2*C221*0.5f*w0; cf[1]=PW2*C221*(S32*w2 - 0.5f*w4); cf[2]=PW2*C221*(-0.5f*w1); }
        else { cf[0]=PW2*C221*0.5f*w1; cf[1]=PW2*C221*0.5f*w3; cf[2]=PW2*C221*(-w0); }
        int offs[3] = { 128 + m0, 192 + m0, 256 + m0 };
        emit_dot<3>(dst, x1, offs, cf);
      }
    } else if (u0 < 288) {          // (2,0,2)
      int m0 = u0 - 256;
      float cf[1] = { PW2 * C220 * s };
      int offs[1] = { 320 + K * 32 + m0 };
      emit_dot<1>(dst, x1, offs, cf);
    } else if (u0 < 320) {          // (2,1,2) zero-pruned
      int m0 = u0 - 288;
      if constexpr (K == 0) {
        float cf[3] = { PW2*C221*0.5f*v1, PW2*C221*(-0.5f*v0), PW2*C221*v2 };
        int offs[3] = { 352 + m0, 416 + m0, 448 + m0 };
        emit_dot<3>(dst, x1, offs, cf);
      } else if constexpr (K == 1) {
        float cf[4] = { PW2*C221*(-0.5f*v1), PW2*C221*(-S32*v0), PW2*C221*0.5f*v2, PW2*C221*(-0.5f*v0) };
        int offs[4] = { 320 + m0, 384 + m0, 416 + m0, 448 + m0 };
        emit_dot<4>(dst, x1, offs, cf);
      } else if constexpr (K == 2) {
        float cf[2] = { PW2*C221*S32*v0, PW2*C221*(-S32*v1) };
        int offs[2] = { 352 + m0, 416 + m0 };
        emit_dot<2>(dst, x1, offs, cf);
      } else if constexpr (K == 3) {
        float cf[4] = { PW2*C221*0.5f*v0, PW2*C221*(-0.5f*v2), PW2*C221*S32*v1, PW2*C221*(-0.5f*v1) };
        int offs[4] = { 320 + m0, 352 + m0, 384 + m0, 448 + m0 };
        emit_dot<4>(dst, x1, offs, cf);
      } else {
        float cf[3] = { PW2*C221*(-v2), PW2*C221*0.5f*v0, PW2*C221*0.5f*v1 };
        int offs[3] = { 320 + m0, 352 + m0, 416 + m0 };
        emit_dot<3>(dst, x1, offs, cf);
      }
    } else {                        // (2,2,2) zero-pruned
      int m0 = u0 - 320;
      if constexpr (K == 0) {
        float cf[4] = { PW2*C222*(-CA*w2), PW2*C222*HR*w3, PW2*C222*(-CA*w0), PW2*C222*HR*w1 };
        int offs[4] = { 320 + m0, 352 + m0, 384 + m0, 416 + m0 };
        emit_dot<4>(dst, x1, offs, cf);
      } else if constexpr (K == 4) {
        float cf[4] = { PW2*C222*(-HR*w1), PW2*C222*(-CA*w4), PW2*C222*HR*w3, PW2*C222*(-CA*w2) };
        int offs[4] = { 352 + m0, 384 + m0, 416 + m0, 448 + m0 };
        emit_dot<4>(dst, x1, offs, cf);
      } else {
        float cf[5];
        if constexpr (K == 1) { cf[0]=PW2*C222*HR*w3; cf[1]=PW2*C222*(HA*w2 - HR*w4); cf[2]=PW2*C222*HA*w1; cf[3]=PW2*C222*HR*w0; cf[4]=PW2*C222*(-HR*w1); }
        else if constexpr (K == 2) { cf[0]=PW2*C222*(-CA*w0); cf[1]=PW2*C222*HA*w1; cf[2]=PW2*C222*CA*w2; cf[3]=PW2*C222*HA*w3; cf[4]=PW2*C222*(-CA*w4); }
        else { cf[0]=PW2*C222*HR*w1; cf[1]=PW2*C222*HR*w0; cf[2]=PW2*C222*HA*w3; cf[3]=PW2*C222*(HA*w2 + HR*w4); cf[4]=PW2*C222*HR*w3; }
        int offs[5] = { 320 + m0, 352 + m0, 384 + m0, 416 + m0, 448 + m0 };
        emit_dot<5>(dst, x1, offs, cf);
      }
    }
  }
}

// ---------------- Fused TP kernel --------------------------------------------
// LDS map (bytes):
//   [0, 24576)      Tbuf0 (32 x 384 ush, XOR-swizzled)
//   [24576, 49152)  Tbuf1
//   gateU (ush 32x232 = 14848)  aliases [0, 14848)      (dead before build0)
//   rbfpadU (ush 32x40 = 2560)  aliases [24576, 27136)  (dead before build1<0>)
//   [49152, 79872)  X1 (ush 32x480)
//   [79872, 81024)  Rsh (fp32 32x9)
//   [81024, 81152)  Edst; [81152, 81280) Esrc
__global__ __launch_bounds__(BS, 4) void tp_fused_kernel(
    const float* __restrict__ rbf, const float* __restrict__ rsh,
    const int* __restrict__ ei, const float* __restrict__ s_out,
    const float* __restrict__ sph_in,
    const unsigned short* __restrict__ W0g, const unsigned short* __restrict__ W1g,
    const unsigned short* __restrict__ W2g, const unsigned short* __restrict__ Wfq,
    float* __restrict__ out0, float* __restrict__ out1)
{
  __shared__ __align__(16) unsigned char smem[81280];
  unsigned short* Tb0 = (unsigned short*)smem;
  unsigned short* Tb1 = (unsigned short*)(smem + 24576);
  unsigned short* gateU = (unsigned short*)smem;
  unsigned short* rbfpadU = (unsigned short*)(smem + 24576);
  unsigned short* X1u = (unsigned short*)(smem + 49152);
  float* RshF = (float*)(smem + 79872);
  int* EdstS = (int*)(smem + 81024);
  int* EsrcS = (int*)(smem + 81152);

  const int tid = threadIdx.x;
  const int wid = tid >> 6, lane = tid & 63;
  const int r = lane & 15, kl = lane >> 4;

  auto MFMA = [](v8bf a, v8bf b, f32x4 c) {
    return __builtin_amdgcn_mfma_f32_16x16x32_bf16(a, b, c, 0, 0, 0);
  };
  auto ldw = [&](const unsigned short* base, int fid) {
    return __builtin_bit_cast(v8bf, *(const us8v*)&base[fid * 512 + lane * 8]);
  };

  auto mfma_l0 = [&](const unsigned short* T) {
    f32x4 acc0 = {0.f, 0.f, 0.f, 0.f}, acc1 = {0.f, 0.f, 0.f, 0.f};
    #pragma unroll
    for (int kk = 0; kk < 7; ++kk) {
      v8bf b = ldw(W0g, kk * 8 + wid);
      us8v a0 = *(const us8v*)&T[TSW(r, r * 384 + kl * 8 + kk * 32)];
      us8v a1 = *(const us8v*)&T[TSW(r, (16 + r) * 384 + kl * 8 + kk * 32)];
      acc0 = MFMA(__builtin_bit_cast(v8bf, a0), b, acc0);
      acc1 = MFMA(__builtin_bit_cast(v8bf, a1), b, acc1);
    }
    int col = wid * 16 + r;
    #pragma unroll
    for (int j = 0; j < 4; ++j) {
      unsafeAtomicAdd(&out1[(long)EdstS[kl * 4 + j] * SD + col], acc0[j]);
      unsafeAtomicAdd(&out1[(long)EdstS[16 + kl * 4 + j] * SD + col], acc1[j]);
    }
  };

  auto mfma_l1 = [&](const unsigned short* T, int k) {
    const int mt = wid >> 2, nt = wid & 3;
    f32x4 acc = {0.f, 0.f, 0.f, 0.f};
    #pragma unroll
    for (int kk = 0; kk < 12; ++kk) {
      v8bf b = ldw(W1g, kk * 4 + nt);
      us8v a = *(const us8v*)&T[TSW(r, (mt * 16 + r) * 384 + kl * 8 + kk * 32)];
      acc = MFMA(__builtin_bit_cast(v8bf, a), b, acc);
    }
    int col = 128 + (nt * 16 + r) * 3 + k;
    #pragma unroll
    for (int j = 0; j < 4; ++j)
      unsafeAtomicAdd(&out1[(long)EdstS[mt * 16 + kl * 4 + j] * SD + col], acc[j]);
  };

  auto mfma_l2 = [&](const unsigned short* T, int K) {
    const int kh = wid >> 2, mt = (wid >> 1) & 1, ntc = wid & 1;
    f32x4 acc = {0.f, 0.f, 0.f, 0.f};
    #pragma unroll
    for (int q = 0; q < 6; ++q) {
      if (kh == 0 || q < 5) {
        v8bf b = ldw(W2g, q * 4 + kh * 2 + ntc);
        us8v a = *(const us8v*)&T[TSW(r, (mt * 16 + r) * 384 + kh * 192 + q * 32 + kl * 8)];
        acc = MFMA(__builtin_bit_cast(v8bf, a), b, acc);
      }
    }
    int col = 320 + (ntc * 16 + r) * 5 + K;
    #pragma unroll
    for (int j = 0; j < 4; ++j)
      unsafeAtomicAdd(&out1[(long)EdstS[mt * 16 + kl * 4 + j] * SD + col], acc[j]);
  };

  for (int tile = blockIdx.x; tile < NE / 32; tile += gridDim.x) {
    const int e0 = tile * 32;
    // ---- stage ----
    for (int i = tid; i < 32; i += BS) { EdstS[i] = ei[e0 + i]; EsrcS[i] = ei[NE + e0 + i]; }
    for (int i = tid; i < 288; i += BS) RshF[i] = rsh[(long)e0 * 9 + i];
    for (int i = tid; i < 1024; i += BS) {
      int e = i >> 5, b = i & 31;
      rbfpadU[e * 40 + b] = (b < 20) ? f2bfc(rbf[(long)(e0 + e) * NB + b]) : (unsigned short)0;
    }
    __syncthreads();
    // ---- filt MFMA -> gate (bf16 LDS) + scalar msg (atomics) ----
    {
      us8v ra0 = *(const us8v*)&rbfpadU[r * 40 + kl * 8];
      us8v ra1 = *(const us8v*)&rbfpadU[(16 + r) * 40 + kl * 8];
      v8bf av0 = __builtin_bit_cast(v8bf, ra0);
      v8bf av1 = __builtin_bit_cast(v8bf, ra1);
      #pragma unroll
      for (int q = 0; q < 6; ++q) {
        int t44 = wid + q * 8;
        if (t44 < 44) {
          int mt = t44 & 1, nt = t44 >> 1;
          v8bf b = ldw(Wfq, q * 8 + wid);
          f32x4 acc = {0.f, 0.f, 0.f, 0.f};
          acc = MFMA(mt ? av1 : av0, b, acc);
          int gi = nt * 16 + r;
          #pragma unroll
          for (int j = 0; j < 4; ++j) {
            int e = mt * 16 + kl * 4 + j;
            float so = s_out[(long)EsrcS[e] * NH + gi];
            float val = acc[j] * so;
            if (nt < 14) gateU[e * 232 + gi] = f2bfc(val);
            else unsafeAtomicAdd(&out0[(long)EdstS[e] * ND + (gi - 224)], val);
          }
        }
      }
    }
    __syncthreads();
    // ---- X1 build (bf16, l1/l2 component-transposed; vectorized gate) ----
    for (int it = tid; it < 1920; it += BS) {
      int e = it / 60, cb = it - e * 60, c0 = cb * 8;
      long srow = (long)EsrcS[e] * SD;
      v8bf o;
      if (c0 < 128) {
        us8v gv = *(const us8v*)&gateU[e * 232 + c0];
        const float4 sa = *(const float4*)&sph_in[srow + c0];
        const float4 sb = *(const float4*)&sph_in[srow + c0 + 4];
        float sv[8] = {sa.x, sa.y, sa.z, sa.w, sb.x, sb.y, sb.z, sb.w};
        #pragma unroll
        for (int i = 0; i < 8; ++i) o[i] = (__bf16)(sv[i] * bf2f(gv[i]));
      } else if (c0 < 320) {
        int m = (c0 - 128) >> 6, mul0 = (c0 - 128) & 63;
        us8v gv = *(const us8v*)&gateU[e * 232 + 128 + mul0];
        #pragma unroll
        for (int i = 0; i < 8; ++i)
          o[i] = (__bf16)(sph_in[srow + 128 + (mul0 + i) * 3 + m] * bf2f(gv[i]));
      } else {
        int m = (c0 - 320) >> 5, mul0 = (c0 - 320) & 31;
        us8v gv = *(const us8v*)&gateU[e * 232 + 192 + mul0];
        #pragma unroll
        for (int i = 0; i < 8; ++i)
          o[i] = (__bf16)(sph_in[srow + 320 + (mul0 + i) * 5 + m] * bf2f(gv[i]));
      }
      *(us8v*)&X1u[e * 480 + c0] = __builtin_bit_cast(us8v, o);
    }
    __syncthreads();
    // ---- 9 phases, double-buffered T ----
    build0(Tb0, X1u, RshF, tid); __syncthreads();
    build1<0>(Tb1, X1u, RshF, tid); mfma_l0(Tb0); __syncthreads();
    build1<1>(Tb0, X1u, RshF, tid); mfma_l1(Tb1, 0); __syncthreads();
    build1<2>(Tb1, X1u, RshF, tid); mfma_l1(Tb0, 1); __syncthreads();
    build2<0>(Tb0, X1u, RshF, tid); mfma_l1(Tb1, 2); __syncthreads();
    build2<1>(Tb1, X1u, RshF, tid); mfma_l2(Tb0, 0); __syncthreads();
    build2<2>(Tb0, X1u, RshF, tid); mfma_l2(Tb1, 1); __syncthreads();
    build2<3>(Tb1, X1u, RshF, tid); mfma_l2(Tb0, 2); __syncthreads();
    build2<4>(Tb0, X1u, RshF, tid); mfma_l2(Tb1, 3); __syncthreads();
    mfma_l2(Tb0, 4); __syncthreads();
  }
}

extern "C" void kernel_launch(void* const* d_in, const int* in_sizes, int n_in,
                              void* d_out, int out_size, void* d_ws, size_t ws_size,
                              hipStream_t stream)
{
  const float* xs   = (const float*)d_in[0];
  const float* xsph = (const float*)d_in[1];
  const float* rbf  = (const float*)d_in[2];
  const float* rsh  = (const float*)d_in[3];
  const int*   ei   = (const int*)d_in[4];
  const float* lnw  = (const float*)d_in[5];
  const float* lnb  = (const float*)d_in[6];
  const float* o3w  = (const float*)d_in[7];
  const float* o3b  = (const float*)d_in[8];
  const float* w1   = (const float*)d_in[9];
  const float* b1   = (const float*)d_in[10];
  const float* w2   = (const float*)d_in[11];
  const float* b2   = (const float*)d_in[12];
  const float* rbfw = (const float*)d_in[13];
  const float* tpw  = (const float*)d_in[14];

  float* out0 = (float*)d_out;
  float* out1 = out0 + (size_t)NN * ND;

  float* ws      = (float*)d_ws;
  float* s_in    = ws;                            // 10000*128
  float* sph_in  = ws + (size_t)NN * ND;          // 10000*480
  float* s_out   = ws + (size_t)NN * (ND + SD);   // 10000*352
  unsigned short* wbase = (unsigned short*)(ws + (size_t)NN * (ND + SD + NH));
  unsigned short* W0g = wbase;              // 28672
  unsigned short* W1g = wbase + 28672;      // 24576
  unsigned short* W2g = wbase + 53248;      // 12288
  unsigned short* Wfq = wbase + 65536;      // 24576   (total 90112 ush)

  prep_w_kernel<<<352, 256, 0, stream>>>(tpw, rbfw, W0g, W1g, W2g, Wfq);
  node_ln_kernel<<<NN, 128, 0, stream>>>(xs, xsph, lnw, lnb, o3w, o3b, s_in, sph_in, out0, out1);
  mlp_kernel<<<NN / NPB, 256, 0, stream>>>(s_in, w1, b1, w2, b2, s_out);
  tp_fused_kernel<<<512, BS, 0, stream>>>(rbf, rsh, ei, s_out, sph_in,
                                          W0g, W1g, W2g, Wfq, out0, out1);
}

// Round 4
// 645.089 us; speedup vs baseline: 5.9039x; 1.5723x over previous
//
#include <hip/hip_runtime.h>

#define NN 10000
#define NE 100000
#define ND 128
#define NB 20
#define NIR 224
#define NH 352
#define SD 480
#define BS 512

// CG / normalization constants (verified in R1/R2)
#define CR   0.70710678118654752f
#define CA   0.40824829046386302f
#define HA   0.20412414523193151f
#define HR   0.35355339059327376f
#define C110 0.57735026918962576f
#define C220 0.44721359549995794f
#define C111 0.40824829046386302f
#define C11X 0.44721359549995794f
#define C221 0.36514837167011074f
#define C222 0.58554004376912270f
#define S32  0.86602540378443865f
#define PW0  0.066815310478106094f
#define PW1  0.088388347648318447f
#define PW2  0.11918321088232916f

typedef __bf16 v8bf __attribute__((ext_vector_type(8)));
typedef unsigned short us8v __attribute__((ext_vector_type(8)));
typedef float f32x4 __attribute__((ext_vector_type(4)));

__device__ __forceinline__ unsigned short f2bfc(float f) {
  __bf16 h = (__bf16)f;
  return __builtin_bit_cast(unsigned short, h);
}
__device__ __forceinline__ float bf2f(unsigned short h) {
  unsigned int u = ((unsigned int)h) << 16;
  return __builtin_bit_cast(float, u);
}

__device__ __forceinline__ float warpReduceSum(float v) {
  #pragma unroll
  for (int off = 32; off > 0; off >>= 1) v += __shfl_down(v, off, 64);
  return v;
}

// ---------------- Kernel 1: scalar LN + O3 LN ------------------------------
// (out1 base value now produced by merge_kernel; only out0 written here)
__global__ __launch_bounds__(128) void node_ln_kernel(
    const float* __restrict__ xs, const float* __restrict__ xsph,
    const float* __restrict__ lnw, const float* __restrict__ lnb,
    const float* __restrict__ o3w, const float* __restrict__ o3b,
    float* __restrict__ s_in, float* __restrict__ sph_in,
    float* __restrict__ out0)
{
  const int n = blockIdx.x, t = threadIdx.x;
  __shared__ float red[4];

  auto reduce2 = [&](float a, float b) {
    a = warpReduceSum(a); b = warpReduceSum(b);
    if ((t & 63) == 0) { red[(t >> 6) * 2] = a; red[(t >> 6) * 2 + 1] = b; }
    __syncthreads();
    float ra = red[0] + red[2], rb = red[1] + red[3];
    __syncthreads();
    return make_float2(ra, rb);
  };

  float x = xs[n * ND + t];
  float2 sr = reduce2(x, x * x);
  float mu = sr.x * (1.f / ND);
  float var = sr.y * (1.f / ND) - mu * mu;
  float y = (x - mu) * rsqrtf(var + 1e-5f) * lnw[t] + lnb[t];
  s_in[n * ND + t] = y; out0[n * ND + t] = y;

  float f = xsph[n * SD + t];
  float2 r0 = reduce2(f, f * f);
  float m0 = r0.x * (1.f / 128.f);
  float nrm0 = r0.y * (1.f / 128.f) - m0 * m0;
  float y0 = (f - m0) * rsqrtf(nrm0 + 1e-5f) * o3w[t] + o3b[t];
  sph_in[n * SD + t] = y0;

  float f1a = xsph[n * SD + 128 + t];
  float f1b = (t < 64) ? xsph[n * SD + 256 + t] : 0.f;
  float2 r1 = reduce2(f1a * f1a + f1b * f1b, 0.f);
  float rs1 = rsqrtf(r1.x * (1.f / 192.f) + 1e-5f);
  sph_in[n * SD + 128 + t] = f1a * rs1 * o3w[128 + t / 3];
  if (t < 64)
    sph_in[n * SD + 256 + t] = f1b * rs1 * o3w[128 + (128 + t) / 3];

  float f2a = xsph[n * SD + 320 + t];
  float f2b = (t < 32) ? xsph[n * SD + 448 + t] : 0.f;
  float2 r2 = reduce2(f2a * f2a + f2b * f2b, 0.f);
  float rs2 = rsqrtf(r2.x * (1.f / 160.f) + 1e-5f);
  sph_in[n * SD + 320 + t] = f2a * rs2 * o3w[192 + t / 5];
  if (t < 32)
    sph_in[n * SD + 448 + t] = f2b * rs2 * o3w[192 + (128 + t) / 5];
}

// ---------------- Kernel 2: node MLP (unchanged, verified) ------------------
#define NPB 8
__global__ __launch_bounds__(256) void mlp_kernel(
    const float* __restrict__ s_in, const float* __restrict__ w1,
    const float* __restrict__ b1, const float* __restrict__ w2,
    const float* __restrict__ b2, float* __restrict__ s_out)
{
  __shared__ float sIn[NPB][ND];
  __shared__ float sH[NPB][ND];
  const int t = threadIdx.x;
  const int n0 = blockIdx.x * NPB;
  for (int i = t; i < NPB * ND; i += 256) sIn[i >> 7][i & 127] = s_in[n0 * ND + i];
  __syncthreads();
  {
    const int j = t & 127, g = t >> 7;
    float acc[4] = {0.f, 0.f, 0.f, 0.f};
    for (int k = 0; k < ND; ++k) {
      float w = w1[k * ND + j];
      #pragma unroll
      for (int i = 0; i < 4; ++i) acc[i] = fmaf(sIn[g + 2 * i][k], w, acc[i]);
    }
    #pragma unroll
    for (int i = 0; i < 4; ++i) {
      float z = acc[i] + b1[j];
      sH[g + 2 * i][j] = z / (1.f + __expf(-z));
    }
  }
  __syncthreads();
  for (int jb = 0; jb < 2; ++jb) {
    int j = jb * 256 + t;
    if (j < NH) {
      float acc[NPB];
      #pragma unroll
      for (int i = 0; i < NPB; ++i) acc[i] = b2[j];
      for (int k = 0; k < ND; ++k) {
        float w = w2[k * NH + j];
        #pragma unroll
        for (int i = 0; i < NPB; ++i) acc[i] = fmaf(sH[i][k], w, acc[i]);
      }
      #pragma unroll
      for (int i = 0; i < NPB; ++i) s_out[(n0 + i) * NH + j] = acc[i];
    }
  }
}

// ---------------- W element fetchers (tpw fp32 layout, verified offsets) ----
__device__ __forceinline__ float wc0(const float* w, int u, int j) {
  int off = (u < 128) ? u * 128 : (u < 192) ? 16384 + (u - 128) * 128 : 24576 + (u - 192) * 128;
  return w[off + j];
}
__device__ __forceinline__ float wc1(const float* w, int u, int j) {
  int off = (u < 128) ? 28672 + u * 64 : (u < 192) ? 36864 + (u - 128) * 64
          : (u < 256) ? 40960 + (u - 192) * 64 : (u < 320) ? 45056 + (u - 256) * 64
          : (u < 352) ? 49152 + (u - 320) * 64 : 51200 + (u - 352) * 64;
  return w[off + j];
}
__device__ __forceinline__ float wc2(const float* w, int u, int j) {
  int off = (u < 128) ? 53248 + u * 32 : (u < 192) ? 57344 + (u - 128) * 32
          : (u < 256) ? 59392 + (u - 192) * 32 : (u < 288) ? 61440 + (u - 256) * 32
          : (u < 320) ? 62464 + (u - 288) * 32 : 63488 + (u - 320) * 32;
  return w[off + j];
}

// ---------------- Prep kernel: pre-swizzle W into bf16 fragment layout ------
__global__ __launch_bounds__(256) void prep_w_kernel(
    const float* __restrict__ tpw, const float* __restrict__ rbf_w,
    unsigned short* __restrict__ W0g, unsigned short* __restrict__ W1g,
    unsigned short* __restrict__ W2g, unsigned short* __restrict__ Wfq)
{
  int gid = blockIdx.x * 256 + threadIdx.x;
  int i = gid & 7, lane = (gid >> 3) & 63;
  int r = lane & 15, kl = lane >> 4;
  if (gid < 28672) {
    int fid = gid >> 9, kk = fid >> 3, wid = fid & 7;
    W0g[gid] = f2bfc(wc0(tpw, kk * 32 + kl * 8 + i, wid * 16 + r));
  } else if (gid < 53248) {
    int g = gid - 28672, fid = g >> 9, kk = fid >> 2, nt = fid & 3;
    W1g[g] = f2bfc(wc1(tpw, kk * 32 + kl * 8 + i, nt * 16 + r));
  } else if (gid < 65536) {
    int g = gid - 53248, fid = g >> 9, q = fid >> 2, kh = (fid >> 1) & 1, ntc = fid & 1;
    int kk = kh * 6 + q;
    W2g[g] = (kk < 11) ? f2bfc(wc2(tpw, kk * 32 + kl * 8 + i, ntc * 16 + r)) : (unsigned short)0;
  } else if (gid < 90112) {
    int g = gid - 65536, fid = g >> 9, q = fid >> 3, wid = fid & 7;
    int t44 = wid + q * 8, nt = t44 >> 1, k = kl * 8 + i;
    Wfq[g] = (t44 < 44 && k < 20) ? f2bfc(rbf_w[k * NH + nt * 16 + r]) : (unsigned short)0;
  }
}

// T-element emitter: tv[i] = sum_m cf[m] * x1vec[m][i], packed to bf16x8.
template<int M>
__device__ __forceinline__ void emit_dot(unsigned short* dst, const unsigned short* x1,
                                         const int* offs, const float* cf) {
  us8v xv[M];
  #pragma unroll
  for (int m = 0; m < M; ++m) xv[m] = *(const us8v*)&x1[offs[m]];
  v8bf o;
  #pragma unroll
  for (int i = 0; i < 8; ++i) {
    float a = 0.f;
    #pragma unroll
    for (int m = 0; m < M; ++m) a = fmaf(cf[m], bf2f(xv[m][i]), a);
    o[i] = (__bf16)a;
  }
  *(us8v*)dst = __builtin_bit_cast(us8v, o);
}

// ---------------- T-slice builders ------------------------------------------
#define TSW(e, idx) ((idx) ^ (((e) & 7) << 3))

__device__ __forceinline__ void build0(unsigned short* Tb, const unsigned short* X1u,
                                       const float* RshF, int tid) {
  for (int it = tid; it < 32 * 28; it += BS) {
    int e = it / 28, ub = it - e * 28, u0 = ub * 8;
    const float* R = &RshF[e * 9];
    const unsigned short* x1 = &X1u[e * 480];
    unsigned short* dst = Tb + TSW(e, e * 384 + u0);
    if (u0 < 128) {
      float cf[1] = { PW0 * R[0] };
      int offs[1] = { u0 };
      emit_dot<1>(dst, x1, offs, cf);
    } else if (u0 < 192) {
      int m0 = u0 - 128;
      float cf[3] = { PW0 * C110 * R[1], PW0 * C110 * R[2], PW0 * C110 * R[3] };
      int offs[3] = { 128 + m0, 192 + m0, 256 + m0 };
      emit_dot<3>(dst, x1, offs, cf);
    } else {
      int m0 = u0 - 192;
      float cf[5] = { PW0 * C220 * R[4], PW0 * C220 * R[5], PW0 * C220 * R[6],
                      PW0 * C220 * R[7], PW0 * C220 * R[8] };
      int offs[5] = { 320 + m0, 352 + m0, 384 + m0, 416 + m0, 448 + m0 };
      emit_dot<5>(dst, x1, offs, cf);
    }
  }
}

template<int k>
__device__ __forceinline__ void build1(unsigned short* Tb, const unsigned short* X1u,
                                       const float* RshF, int tid) {
  for (int it = tid; it < 32 * 48; it += BS) {
    int e = it / 48, ub = it - e * 48, u0 = ub * 8;
    const float* R = &RshF[e * 9];
    const unsigned short* x1 = &X1u[e * 480];
    unsigned short* dst = Tb + TSW(e, e * 384 + u0);
    const float s = R[0], v0 = R[1], v1 = R[2], v2 = R[3];
    const float w0 = R[4], w1 = R[5], w2 = R[6], w3 = R[7], w4 = R[8];
    if (u0 < 128) {                 // (0,1,1)
      float cf[1] = { PW1 * C110 * R[1 + k] };
      int offs[1] = { u0 };
      emit_dot<1>(dst, x1, offs, cf);
    } else if (u0 < 192) {          // (1,0,1)
      float cf[1] = { PW1 * C110 * s };
      int offs[1] = { 128 + k * 64 + (u0 - 128) };
      emit_dot<1>(dst, x1, offs, cf);
    } else if (u0 < 256) {          // (1,1,1)
      constexpr int ka = (k + 1) % 3, kb = (k + 2) % 3;
      int m0 = u0 - 192;
      float cf[2] = { PW1 * C111 * R[1 + kb], -PW1 * C111 * R[1 + ka] };
      int offs[2] = { 128 + ka * 64 + m0, 128 + kb * 64 + m0 };
      emit_dot<2>(dst, x1, offs, cf);
    } else if (u0 < 320) {          // (1,2,1)
      int m0 = u0 - 256;
      float cf[3];
      if constexpr (k == 0) { cf[0] = PW1*C11X*(-CA*w2 + CR*w4); cf[1] = PW1*C11X*CR*w0; cf[2] = PW1*C11X*CR*w3; }
      else if constexpr (k == 1) { cf[0] = PW1*C11X*CR*w0; cf[1] = PW1*C11X*(-CA*w2 - CR*w4); cf[2] = PW1*C11X*CR*w1; }
      else { cf[0] = PW1*C11X*CR*w3; cf[1] = PW1*C11X*CR*w1; cf[2] = PW1*C11X*2.f*CA*w2; }
      int offs[3] = { 128 + m0, 192 + m0, 256 + m0 };
      emit_dot<3>(dst, x1, offs, cf);
    } else if (u0 < 352) {          // (2,1,1) zero-pruned
      int m0 = u0 - 320;
      if constexpr (k == 0) {
        float cf[4] = { PW1*C11X*CR*v1, PW1*C11X*(-CA*v0), PW1*C11X*CR*v2, PW1*C11X*CR*v0 };
        int offs[4] = { 320 + m0, 384 + m0, 416 + m0, 448 + m0 };
        emit_dot<4>(dst, x1, offs, cf);
      } else if constexpr (k == 1) {
        float cf[4] = { PW1*C11X*CR*v0, PW1*C11X*CR*v2, PW1*C11X*(-CA*v1), PW1*C11X*(-CR*v1) };
        int offs[4] = { 320 + m0, 352 + m0, 384 + m0, 448 + m0 };
        emit_dot<4>(dst, x1, offs, cf);
      } else {
        float cf[3] = { PW1*C11X*CR*v1, PW1*C11X*2.f*CA*v2, PW1*C11X*CR*v0 };
        int offs[3] = { 352 + m0, 384 + m0, 416 + m0 };
        emit_dot<3>(dst, x1, offs, cf);
      }
    } else {                        // (2,2,1) zero-pruned
      int m0 = u0 - 352;
      if constexpr (k == 0) {
        float cf[5] = { PW1*C221*0.5f*w3, PW1*C221*(S32*w2 + 0.5f*w4), PW1*C221*(-S32*w1),
                        PW1*C221*(-0.5f*w0), PW1*C221*(-0.5f*w1) };
        int offs[5] = { 320 + m0, 352 + m0, 384 + m0, 416 + m0, 448 + m0 };
        emit_dot<5>(dst, x1, offs, cf);
      } else if constexpr (k == 1) {
        float cf[5] = { PW1*C221*(-0.5f*w1), PW1*C221*0.5f*w0, PW1*C221*S32*w3,
                        PW1*C221*(-S32*w2 + 0.5f*w4), PW1*C221*(-0.5f*w3) };
        int offs[5] = { 320 + m0, 352 + m0, 384 + m0, 416 + m0, 448 + m0 };
        emit_dot<5>(dst, x1, offs, cf);
      } else {
        float cf[4] = { PW1*C221*(-w4), PW1*C221*(-0.5f*w3), PW1*C221*0.5f*w1, PW1*C221*w0 };
        int offs[4] = { 320 + m0, 352 + m0, 416 + m0, 448 + m0 };
        emit_dot<4>(dst, x1, offs, cf);
      }
    }
  }
}

template<int K>
__device__ __forceinline__ void build2(unsigned short* Tb, const unsigned short* X1u,
                                       const float* RshF, int tid) {
  for (int it = tid; it < 32 * 44; it += BS) {
    int e = it / 44, ub = it - e * 44, u0 = ub * 8;
    const float* R = &RshF[e * 9];
    const unsigned short* x1 = &X1u[e * 480];
    unsigned short* dst = Tb + TSW(e, e * 384 + u0);
    const float s = R[0], v0 = R[1], v1 = R[2], v2 = R[3];
    const float w0 = R[4], w1 = R[5], w2 = R[6], w3 = R[7], w4 = R[8];
    if (u0 < 128) {                 // (0,2,2)
      float cf[1] = { PW2 * C220 * R[4 + K] };
      int offs[1] = { u0 };
      emit_dot<1>(dst, x1, offs, cf);
    } else if (u0 < 192) {          // (1,1,2) zero-pruned
      int m0 = u0 - 128;
      if constexpr (K == 0) {
        float cf[2] = { PW2*C11X*CR*v1, PW2*C11X*CR*v0 };
        int offs[2] = { 128 + m0, 192 + m0 };
        emit_dot<2>(dst, x1, offs, cf);
      } else if constexpr (K == 1) {
        float cf[2] = { PW2*C11X*CR*v2, PW2*C11X*CR*v1 };
        int offs[2] = { 192 + m0, 256 + m0 };
        emit_dot<2>(dst, x1, offs, cf);
      } else if constexpr (K == 2) {
        float cf[3] = { PW2*C11X*(-CA*v0), PW2*C11X*(-CA*v1), PW2*C11X*2.f*CA*v2 };
        int offs[3] = { 128 + m0, 192 + m0, 256 + m0 };
        emit_dot<3>(dst, x1, offs, cf);
      } else if constexpr (K == 3) {
        float cf[2] = { PW2*C11X*CR*v2, PW2*C11X*CR*v0 };
        int offs[2] = { 128 + m0, 256 + m0 };
        emit_dot<2>(dst, x1, offs, cf);
      } else {
        float cf[2] = { PW2*C11X*CR*v0, PW2*C11X*(-CR*v1) };
        int offs[2] = { 128 + m0, 192 + m0 };
        emit_dot<2>(dst, x1, offs, cf);
      }
    } else if (u0 < 256) {          // (1,2,2) zero-pruned
      int m0 = u0 - 192;
      if constexpr (K == 2) {
        float cf[2] = { PW2*C221*S32*w1, PW2*C221*(-S32*w3) };
        int offs[2] = { 128 + m0, 192 + m0 };
        emit_dot<2>(dst, x1, offs, cf);
      } else {
        float cf[3];
        if constexpr (K == 0) { cf[0]=PW2*C221*(-0.5f*w3); cf[1]=PW2*C221*0.5f*w1; cf[2]=PW2*C221*w4; }
        else if constexpr (K == 1) { cf[0]=PW2*C221*(-S32*w2 - 0.5f*w4); cf[1]=PW2*C221*(-0.5f*w0); cf[2]=PW2*C221*0.5f*w3; }
        else if constexpr (K == 3) { cf[0]=PW2*C221*0.5f*w0; cf[1]=PW2*C221*(S32*w2 - 0.5f*w4); cf[2]=PW2*C221*(-0.5f*w1); }
        else { cf[0]=PW2*C221*0.5f*w1; cf[1]=PW2*C221*0.5f*w3; cf[2]=PW2*C221*(-w0); }
        int offs[3] = { 128 + m0, 192 + m0, 256 + m0 };
        emit_dot<3>(dst, x1, offs, cf);
      }
    } else if (u0 < 288) {          // (2,0,2)
      int m0 = u0 - 256;
      float cf[1] = { PW2 * C220 * s };
      int offs[1] = { 320 + K * 32 + m0 };
      emit_dot<1>(dst, x1, offs, cf);
    } else if (u0 < 320) {          // (2,1,2) zero-pruned
      int m0 = u0 - 288;
      if constexpr (K == 0) {
        float cf[3] = { PW2*C221*0.5f*v1, PW2*C221*(-0.5f*v0), PW2*C221*v2 };
        int offs[3] = { 352 + m0, 416 + m0, 448 + m0 };
        emit_dot<3>(dst, x1, offs, cf);
      } else if constexpr (K == 1) {
        float cf[4] = { PW2*C221*(-0.5f*v1), PW2*C221*(-S32*v0), PW2*C221*0.5f*v2, PW2*C221*(-0.5f*v0) };
        int offs[4] = { 320 + m0, 384 + m0, 416 + m0, 448 + m0 };
        emit_dot<4>(dst, x1, offs, cf);
      } else if constexpr (K == 2) {
        float cf[2] = { PW2*C221*S32*v0, PW2*C221*(-S32*v1) };
        int offs[2] = { 352 + m0, 416 + m0 };
        emit_dot<2>(dst, x1, offs, cf);
      } else if constexpr (K == 3) {
        float cf[4] = { PW2*C221*0.5f*v0, PW2*C221*(-0.5f*v2), PW2*C221*S32*v1, PW2*C221*(-0.5f*v1) };
        int offs[4] = { 320 + m0, 352 + m0, 384 + m0, 448 + m0 };
        emit_dot<4>(dst, x1, offs, cf);
      } else {
        float cf[3] = { PW2*C221*(-v2), PW2*C221*0.5f*v0, PW2*C221*0.5f*v1 };
        int offs[3] = { 320 + m0, 352 + m0, 416 + m0 };
        emit_dot<3>(dst, x1, offs, cf);
      }
    } else {                        // (2,2,2) zero-pruned
      int m0 = u0 - 320;
      if constexpr (K == 0) {
        float cf[4] = { PW2*C222*(-CA*w2), PW2*C222*HR*w3, PW2*C222*(-CA*w0), PW2*C222*HR*w1 };
        int offs[4] = { 320 + m0, 352 + m0, 384 + m0, 416 + m0 };
        emit_dot<4>(dst, x1, offs, cf);
      } else if constexpr (K == 4) {
        float cf[4] = { PW2*C222*(-HR*w1), PW2*C222*(-CA*w4), PW2*C222*HR*w3, PW2*C222*(-CA*w2) };
        int offs[4] = { 352 + m0, 384 + m0, 416 + m0, 448 + m0 };
        emit_dot<4>(dst, x1, offs, cf);
      } else {
        float cf[5];
        if constexpr (K == 1) { cf[0]=PW2*C222*HR*w3; cf[1]=PW2*C222*(HA*w2 - HR*w4); cf[2]=PW2*C222*HA*w1; cf[3]=PW2*C222*HR*w0; cf[4]=PW2*C222*(-HR*w1); }
        else if constexpr (K == 2) { cf[0]=PW2*C222*(-CA*w0); cf[1]=PW2*C222*HA*w1; cf[2]=PW2*C222*CA*w2; cf[3]=PW2*C222*HA*w3; cf[4]=PW2*C222*(-CA*w4); }
        else { cf[0]=PW2*C222*HR*w1; cf[1]=PW2*C222*HR*w0; cf[2]=PW2*C222*HA*w3; cf[3]=PW2*C222*(HA*w2 + HR*w4); cf[4]=PW2*C222*HR*w3; }
        int offs[5] = { 320 + m0, 352 + m0, 384 + m0, 416 + m0, 448 + m0 };
        emit_dot<5>(dst, x1, offs, cf);
      }
    }
  }
}

// ---------------- Fused TP kernel --------------------------------------------
// Atomic scatter now goes to out1T (component-major): every 16-lane atomic
// group hits 16 CONSECUTIVE dwords (full 64B lines) -> minimal RMW traffic.
__global__ __launch_bounds__(BS, 4) void tp_fused_kernel(
    const float* __restrict__ rbf, const float* __restrict__ rsh,
    const int* __restrict__ ei, const float* __restrict__ s_out,
    const float* __restrict__ sph_in,
    const unsigned short* __restrict__ W0g, const unsigned short* __restrict__ W1g,
    const unsigned short* __restrict__ W2g, const unsigned short* __restrict__ Wfq,
    float* __restrict__ out0, float* __restrict__ out1T)
{
  __shared__ __align__(16) unsigned char smem[81280];
  unsigned short* Tb0 = (unsigned short*)smem;
  unsigned short* Tb1 = (unsigned short*)(smem + 24576);
  unsigned short* gateU = (unsigned short*)smem;
  unsigned short* rbfpadU = (unsigned short*)(smem + 24576);
  unsigned short* X1u = (unsigned short*)(smem + 49152);
  float* RshF = (float*)(smem + 79872);
  int* EdstS = (int*)(smem + 81024);
  int* EsrcS = (int*)(smem + 81152);

  const int tid = threadIdx.x;
  const int wid = tid >> 6, lane = tid & 63;
  const int r = lane & 15, kl = lane >> 4;

  auto MFMA = [](v8bf a, v8bf b, f32x4 c) {
    return __builtin_amdgcn_mfma_f32_16x16x32_bf16(a, b, c, 0, 0, 0);
  };
  auto ldw = [&](const unsigned short* base, int fid) {
    return __builtin_bit_cast(v8bf, *(const us8v*)&base[fid * 512 + lane * 8]);
  };

  auto mfma_l0 = [&](const unsigned short* T) {
    f32x4 acc0 = {0.f, 0.f, 0.f, 0.f}, acc1 = {0.f, 0.f, 0.f, 0.f};
    #pragma unroll
    for (int kk = 0; kk < 7; ++kk) {
      v8bf b = ldw(W0g, kk * 8 + wid);
      us8v a0 = *(const us8v*)&T[TSW(r, r * 384 + kl * 8 + kk * 32)];
      us8v a1 = *(const us8v*)&T[TSW(r, (16 + r) * 384 + kl * 8 + kk * 32)];
      acc0 = MFMA(__builtin_bit_cast(v8bf, a0), b, acc0);
      acc1 = MFMA(__builtin_bit_cast(v8bf, a1), b, acc1);
    }
    int col = wid * 16 + r;
    #pragma unroll
    for (int j = 0; j < 4; ++j) {
      unsafeAtomicAdd(&out1T[(long)EdstS[kl * 4 + j] * SD + col], acc0[j]);
      unsafeAtomicAdd(&out1T[(long)EdstS[16 + kl * 4 + j] * SD + col], acc1[j]);
    }
  };

  auto mfma_l1 = [&](const unsigned short* T, int k) {
    const int mt = wid >> 2, nt = wid & 3;
    f32x4 acc = {0.f, 0.f, 0.f, 0.f};
    #pragma unroll
    for (int kk = 0; kk < 12; ++kk) {
      v8bf b = ldw(W1g, kk * 4 + nt);
      us8v a = *(const us8v*)&T[TSW(r, (mt * 16 + r) * 384 + kl * 8 + kk * 32)];
      acc = MFMA(__builtin_bit_cast(v8bf, a), b, acc);
    }
    int col = 128 + k * 64 + nt * 16 + r;     // component-major: contiguous in r
    #pragma unroll
    for (int j = 0; j < 4; ++j)
      unsafeAtomicAdd(&out1T[(long)EdstS[mt * 16 + kl * 4 + j] * SD + col], acc[j]);
  };

  auto mfma_l2 = [&](const unsigned short* T, int K) {
    const int kh = wid >> 2, mt = (wid >> 1) & 1, ntc = wid & 1;
    f32x4 acc = {0.f, 0.f, 0.f, 0.f};
    #pragma unroll
    for (int q = 0; q < 6; ++q) {
      if (kh == 0 || q < 5) {
        v8bf b = ldw(W2g, q * 4 + kh * 2 + ntc);
        us8v a = *(const us8v*)&T[TSW(r, (mt * 16 + r) * 384 + kh * 192 + q * 32 + kl * 8)];
        acc = MFMA(__builtin_bit_cast(v8bf, a), b, acc);
      }
    }
    int col = 320 + K * 32 + ntc * 16 + r;    // component-major: contiguous in r
    #pragma unroll
    for (int j = 0; j < 4; ++j)
      unsafeAtomicAdd(&out1T[(long)EdstS[mt * 16 + kl * 4 + j] * SD + col], acc[j]);
  };

  for (int tile = blockIdx.x; tile < NE / 32; tile += gridDim.x) {
    const int e0 = tile * 32;
    // ---- stage ----
    for (int i = tid; i < 32; i += BS) { EdstS[i] = ei[e0 + i]; EsrcS[i] = ei[NE + e0 + i]; }
    for (int i = tid; i < 288; i += BS) RshF[i] = rsh[(long)e0 * 9 + i];
    for (int i = tid; i < 1024; i += BS) {
      int e = i >> 5, b = i & 31;
      rbfpadU[e * 40 + b] = (b < 20) ? f2bfc(rbf[(long)(e0 + e) * NB + b]) : (unsigned short)0;
    }
    __syncthreads();
    // ---- filt MFMA -> gate (bf16 LDS) + scalar msg (atomics, 16-contig) ----
    {
      us8v ra0 = *(const us8v*)&rbfpadU[r * 40 + kl * 8];
      us8v ra1 = *(const us8v*)&rbfpadU[(16 + r) * 40 + kl * 8];
      v8bf av0 = __builtin_bit_cast(v8bf, ra0);
      v8bf av1 = __builtin_bit_cast(v8bf, ra1);
      #pragma unroll
      for (int q = 0; q < 6; ++q) {
        int t44 = wid + q * 8;
        if (t44 < 44) {
          int mt = t44 & 1, nt = t44 >> 1;
          v8bf b = ldw(Wfq, q * 8 + wid);
          f32x4 acc = {0.f, 0.f, 0.f, 0.f};
          acc = MFMA(mt ? av1 : av0, b, acc);
          int gi = nt * 16 + r;
          #pragma unroll
          for (int j = 0; j < 4; ++j) {
            int e = mt * 16 + kl * 4 + j;
            float so = s_out[(long)EsrcS[e] * NH + gi];
            float val = acc[j] * so;
            if (nt < 14) gateU[e * 232 + gi] = f2bfc(val);
            else unsafeAtomicAdd(&out0[(long)EdstS[e] * ND + (gi - 224)], val);
          }
        }
      }
    }
    __syncthreads();
    // ---- X1 build (bf16, component-major l1/l2) ----
    for (int it = tid; it < 1920; it += BS) {
      int e = it / 60, cb = it - e * 60, c0 = cb * 8;
      long srow = (long)EsrcS[e] * SD;
      v8bf o;
      if (c0 < 128) {
        us8v gv = *(const us8v*)&gateU[e * 232 + c0];
        const float4 sa = *(const float4*)&sph_in[srow + c0];
        const float4 sb = *(const float4*)&sph_in[srow + c0 + 4];
        float sv[8] = {sa.x, sa.y, sa.z, sa.w, sb.x, sb.y, sb.z, sb.w};
        #pragma unroll
        for (int i = 0; i < 8; ++i) o[i] = (__bf16)(sv[i] * bf2f(gv[i]));
      } else if (c0 < 320) {
        int m = (c0 - 128) >> 6, mul0 = (c0 - 128) & 63;
        us8v gv = *(const us8v*)&gateU[e * 232 + 128 + mul0];
        #pragma unroll
        for (int i = 0; i < 8; ++i)
          o[i] = (__bf16)(sph_in[srow + 128 + (mul0 + i) * 3 + m] * bf2f(gv[i]));
      } else {
        int m = (c0 - 320) >> 5, mul0 = (c0 - 320) & 31;
        us8v gv = *(const us8v*)&gateU[e * 232 + 192 + mul0];
        #pragma unroll
        for (int i = 0; i < 8; ++i)
          o[i] = (__bf16)(sph_in[srow + 320 + (mul0 + i) * 5 + m] * bf2f(gv[i]));
      }
      *(us8v*)&X1u[e * 480 + c0] = __builtin_bit_cast(us8v, o);
    }
    __syncthreads();
    // ---- 9 phases, double-buffered T ----
    build0(Tb0, X1u, RshF, tid); __syncthreads();
    build1<0>(Tb1, X1u, RshF, tid); mfma_l0(Tb0); __syncthreads();
    build1<1>(Tb0, X1u, RshF, tid); mfma_l1(Tb1, 0); __syncthreads();
    build1<2>(Tb1, X1u, RshF, tid); mfma_l1(Tb0, 1); __syncthreads();
    build2<0>(Tb0, X1u, RshF, tid); mfma_l1(Tb1, 2); __syncthreads();
    build2<1>(Tb1, X1u, RshF, tid); mfma_l2(Tb0, 0); __syncthreads();
    build2<2>(Tb0, X1u, RshF, tid); mfma_l2(Tb1, 1); __syncthreads();
    build2<3>(Tb1, X1u, RshF, tid); mfma_l2(Tb0, 2); __syncthreads();
    build2<4>(Tb0, X1u, RshF, tid); mfma_l2(Tb1, 3); __syncthreads();
    mfma_l2(Tb0, 4); __syncthreads();
  }
}

// ---------------- Merge: out1 = sph_in + transpose(out1T) -------------------
// t indexes the ORIGINAL column; component-major source index computed from it.
__global__ __launch_bounds__(512) void merge_kernel(
    const float* __restrict__ sph_in, const float* __restrict__ out1T,
    float* __restrict__ out1)
{
  const int n = blockIdx.x, t = threadIdx.x;
  if (t < SD) {
    int tT;
    if (t < 128) tT = t;
    else if (t < 320) { int c = t - 128; int mul = c / 3, k = c - mul * 3; tT = 128 + k * 64 + mul; }
    else { int c = t - 320; int mul = c / 5, K = c - mul * 5; tT = 320 + K * 32 + mul; }
    out1[(long)n * SD + t] = sph_in[(long)n * SD + t] + out1T[(long)n * SD + tT];
  }
}

extern "C" void kernel_launch(void* const* d_in, const int* in_sizes, int n_in,
                              void* d_out, int out_size, void* d_ws, size_t ws_size,
                              hipStream_t stream)
{
  const float* xs   = (const float*)d_in[0];
  const float* xsph = (const float*)d_in[1];
  const float* rbf  = (const float*)d_in[2];
  const float* rsh  = (const float*)d_in[3];
  const int*   ei   = (const int*)d_in[4];
  const float* lnw  = (const float*)d_in[5];
  const float* lnb  = (const float*)d_in[6];
  const float* o3w  = (const float*)d_in[7];
  const float* o3b  = (const float*)d_in[8];
  const float* w1   = (const float*)d_in[9];
  const float* b1   = (const float*)d_in[10];
  const float* w2   = (const float*)d_in[11];
  const float* b2   = (const float*)d_in[12];
  const float* rbfw = (const float*)d_in[13];
  const float* tpw  = (const float*)d_in[14];

  float* out0 = (float*)d_out;
  float* out1 = out0 + (size_t)NN * ND;

  float* ws      = (float*)d_ws;
  float* s_in    = ws;                              // 10000*128
  float* sph_in  = ws + (size_t)NN * ND;            // 10000*480
  float* s_out   = ws + (size_t)NN * (ND + SD);     // 10000*352
  float* out1T   = ws + (size_t)NN * (ND + SD + NH);// 10000*480
  unsigned short* wbase = (unsigned short*)(ws + (size_t)NN * (ND + 2 * SD + NH));
  unsigned short* W0g = wbase;              // 28672
  unsigned short* W1g = wbase + 28672;      // 24576
  unsigned short* W2g = wbase + 53248;      // 12288
  unsigned short* Wfq = wbase + 65536;      // 24576

  hipMemsetAsync(out1T, 0, (size_t)NN * SD * sizeof(float), stream);
  prep_w_kernel<<<352, 256, 0, stream>>>(tpw, rbfw, W0g, W1g, W2g, Wfq);
  node_ln_kernel<<<NN, 128, 0, stream>>>(xs, xsph, lnw, lnb, o3w, o3b, s_in, sph_in, out0);
  mlp_kernel<<<NN / NPB, 256, 0, stream>>>(s_in, w1, b1, w2, b2, s_out);
  tp_fused_kernel<<<512, BS, 0, stream>>>(rbf, rsh, ei, s_out, sph_in,
                                          W0g, W1g, W2g, Wfq, out0, out1T);
  merge_kernel<<<NN, 512, 0, stream>>>(sph_in, out1T, out1);
}